// Round 3
// baseline (607.916 us; speedup 1.0000x reference)
//
#include <hip/hip_runtime.h>
#include <math.h>

// Problem constants
#define N_CLASS 64
#define N_SUPPORT 5
#define N_QUERY 64
#define D_IN 1024
#define C_CH 128
#define WIN 5
#define D_FEAT 3200            // C*WIN*WIN
#define NS 320                 // N_CLASS*N_SUPPORT
#define NQ 4096                // N_CLASS*N_QUERY
#define M_ROWS 4416            // NS+NQ
#define M_PAD 4480             // 35 * 128

typedef __bf16 bf16x8 __attribute__((ext_vector_type(8)));
typedef __bf16 bf16x4 __attribute__((ext_vector_type(4)));
typedef float floatx4 __attribute__((ext_vector_type(4)));
typedef __attribute__((address_space(1))) const void* gptr_t;
typedef __attribute__((address_space(3))) void* lptr_t;

__device__ __forceinline__ float waveReduceSum(float v) {
    for (int off = 32; off > 0; off >>= 1) v += __shfl_xor(v, off, 64);
    return v;
}

// ---------------- convert x (xs|xq|zero-pad) -> bf16 [M_PAD][1024] ----------------
__global__ __launch_bounds__(256) void conv_x_kernel(const float* __restrict__ xs,
                                                     const float* __restrict__ xq,
                                                     __bf16* __restrict__ Xb)
{
    const int idx = blockIdx.x * 256 + threadIdx.x;
    const int e = idx * 4;
    if (e >= M_PAD * D_IN) return;
    const int row = e >> 10;
    const int col = e & 1023;
    float4 v = make_float4(0.f, 0.f, 0.f, 0.f);
    if (row < NS)            v = *(const float4*)(xs + (size_t)row * D_IN + col);
    else if (row < M_ROWS)   v = *(const float4*)(xq + (size_t)(row - NS) * D_IN + col);
    __bf16* o = Xb + (size_t)row * D_IN + col;
    o[0] = (__bf16)v.x; o[1] = (__bf16)v.y; o[2] = (__bf16)v.z; o[3] = (__bf16)v.w;
}

// ---------------- convert + transpose W [K][N] f32 -> Wt [N][K] bf16 ----------------
__global__ __launch_bounds__(256) void convT_kernel(const float* __restrict__ W,
                                                    __bf16* __restrict__ Wt,
                                                    int K, int N)
{
    __shared__ float tile[32][33];
    const int tx = threadIdx.x & 31;
    const int ty = threadIdx.x >> 5;
    const int n0 = blockIdx.x * 32;
    const int k0 = blockIdx.y * 32;
#pragma unroll
    for (int i = ty; i < 32; i += 8)
        tile[i][tx] = W[(size_t)(k0 + i) * N + n0 + tx];
    __syncthreads();
#pragma unroll
    for (int i = ty; i < 32; i += 8)
        Wt[(size_t)(n0 + i) * K + k0 + tx] = (__bf16)tile[tx][i];
}

// ---------------- MFMA GEMM: out = act(A @ Bt^T + bias) ----------------
// A [..][K] bf16 row-major, Bt [N][K] bf16 row-major. 128x128 tile, BK=32.
// 1D grid with L2/XCD-aware remap: groups of 8 column-tiles x nby row-tiles,
// col = b&7 within a group -> each XCD keeps one Bt column tile L2-resident.
// LDS layout XOR-swizzled: chunk_pos = k_chunk ^ ((row>>1)&3) -> conflict-free
// bf16x8 fragment reads (2 accesses/bank per quarter-wave phase).
__global__ __launch_bounds__(256) void gemm_bf16(const __bf16* __restrict__ A,
                                                 const __bf16* __restrict__ Bt,
                                                 const float* __restrict__ bias,
                                                 __bf16* __restrict__ out_bf,
                                                 float* __restrict__ out_f32,
                                                 int N, int K, int Mout, int relu,
                                                 int nbx, int nby)
{
    __shared__ __align__(16) char smem[16384];   // sA [128][32] | sB [128][32] bf16

    // ---- block remap ----
    int bx, by;
    {
        const int b  = blockIdx.x;
        const int fg = nbx >> 3;
        const int full = fg * 8 * nby;
        if (b < full) {
            const int g = b / (8 * nby);
            const int r = b - g * 8 * nby;
            bx = g * 8 + (r & 7);
            by = r >> 3;
        } else {
            const int rem = nbx - fg * 8;
            const int r = b - full;
            bx = fg * 8 + r % rem;
            by = r / rem;
        }
    }

    const int t    = threadIdx.x;
    const int lane = t & 63;
    const int w    = t >> 6;
    const int wm   = w >> 1;
    const int wn   = w & 1;
    const int bm   = by * 128;
    const int bn   = bx * 128;

    const int q    = lane >> 4;
    const int r16  = lane & 15;
    const int sw   = (r16 >> 1) & 3;            // read-side swizzle
    const int cA   = (q ^ sw) * 8;              // element offset of k-chunk q

    // staging: lane writes LDS at base+lane*16; choose global chunk so that
    // stored chunk_pos = k_chunk ^ ((row>>1)&3).  row%16 = lane>>2.
    const int srow   = w * 16 + (lane >> 2);    // + j*64
    const int sglob8 = (((lane & 3) ^ ((lane >> 3) & 3))) * 8;

    floatx4 acc[4][4] = {};

    for (int k0 = 0; k0 < K; k0 += 32) {
        __syncthreads();
#pragma unroll
        for (int j = 0; j < 2; ++j) {
            const __bf16* ga = A  + (size_t)(bm + j * 64 + srow) * K + k0 + sglob8;
            const __bf16* gb = Bt + (size_t)(bn + j * 64 + srow) * K + k0 + sglob8;
            char* la = smem +        (j * 256 + w * 64) * 16;
            char* lb = smem + 8192 + (j * 256 + w * 64) * 16;
            __builtin_amdgcn_global_load_lds((gptr_t)ga, (lptr_t)la, 16, 0, 0);
            __builtin_amdgcn_global_load_lds((gptr_t)gb, (lptr_t)lb, 16, 0, 0);
        }
        __syncthreads();

        const __bf16* sAe = (const __bf16*)smem;
        const __bf16* sBe = (const __bf16*)(smem + 8192);
        bf16x8 av[4], bv[4];
#pragma unroll
        for (int mi = 0; mi < 4; ++mi)
            av[mi] = *(const bf16x8*)(sAe + ((wm * 64 + mi * 16 + r16) * 32 + cA));
#pragma unroll
        for (int ni = 0; ni < 4; ++ni)
            bv[ni] = *(const bf16x8*)(sBe + ((wn * 64 + ni * 16 + r16) * 32 + cA));
#pragma unroll
        for (int mi = 0; mi < 4; ++mi)
#pragma unroll
            for (int ni = 0; ni < 4; ++ni)
                acc[mi][ni] = __builtin_amdgcn_mfma_f32_16x16x32_bf16(
                    av[mi], bv[ni], acc[mi][ni], 0, 0, 0);
    }

    // epilogue: C/D layout col=lane&15, row=(lane>>4)*4+reg
#pragma unroll
    for (int ni = 0; ni < 4; ++ni) {
        const int col = bn + wn * 64 + ni * 16 + r16;
        const float bcol = bias[col];
#pragma unroll
        for (int mi = 0; mi < 4; ++mi) {
#pragma unroll
            for (int reg = 0; reg < 4; ++reg) {
                const int row = bm + wm * 64 + mi * 16 + q * 4 + reg;
                if (row < Mout) {
                    float v = acc[mi][ni][reg] + bcol;
                    if (relu) v = fmaxf(v, 0.f);
                    if (out_f32) out_f32[(size_t)row * N + col] = v;
                    else         out_bf [(size_t)row * N + col] = (__bf16)v;
                }
            }
        }
    }
}

// ---------------- Attention stage 1: pooled mean over support rows ----------------
__global__ __launch_bounds__(256) void att1_kernel(const __bf16* __restrict__ z_share,
                                                   float* __restrict__ pm)
{
    __shared__ float s_red[4];
    const int c = blockIdx.x;
    const int t = threadIdx.x;
    float part = 0.f;
    for (int idx = t; idx < NS * 25; idx += 256) {
        const int r = idx / 25, p = idx % 25;
        part += (float)z_share[(size_t)r * D_FEAT + c * 25 + p];
    }
    part = waveReduceSum(part);
    const int lane = t & 63, wid = t >> 6;
    if (lane == 0) s_red[wid] = part;
    __syncthreads();
    if (t == 0)
        pm[c] = (s_red[0] + s_red[1] + s_red[2] + s_red[3]) * (1.0f / (NS * 25));
}

// ---------------- Attention stage 2: matvec + softmax -> w[3200] ----------------
__global__ __launch_bounds__(128) void att2_kernel(const float* __restrict__ pm,
                                                   const float* __restrict__ W_att,
                                                   const float* __restrict__ b_att,
                                                   float* __restrict__ wvec)
{
    __shared__ float s_att[C_CH];
    __shared__ float s_diag[C_CH];
    const int c = threadIdx.x;
    float acc = b_att[c];
    for (int k = 0; k < C_CH; ++k) acc += pm[k] * W_att[k * C_CH + c];
    s_att[c] = acc;
    __syncthreads();
    float m = -INFINITY;
    for (int k = 0; k < C_CH; ++k) m = fmaxf(m, s_att[k]);
    float s = 0.f;
    for (int k = 0; k < C_CH; ++k) s += expf(s_att[k] - m);
    s_diag[c] = expf(acc - m) / s * (float)C_CH;
    __syncthreads();
    for (int j = c; j < D_FEAT; j += C_CH) wvec[j] = s_diag[j / 25];
}

// ---------------- protow: zpw[p][j] = mean_s(z)*w[j] (bf16, pad rows=0), p2, zbias --
__global__ __launch_bounds__(256) void protow_kernel(const __bf16* __restrict__ z,
                                                     const float* __restrict__ wv,
                                                     __bf16* __restrict__ zpw,
                                                     float* __restrict__ p2,
                                                     float* __restrict__ zbias)
{
    __shared__ float s_red[4];
    const int p = blockIdx.x;        // 0..127
    const int t = threadIdx.x;
    if (p >= N_CLASS) {
        for (int j = t; j < D_FEAT; j += 256) zpw[(size_t)p * D_FEAT + j] = (__bf16)0.f;
        if (p == N_CLASS && t < 128) zbias[t] = 0.f;
        return;
    }
    const __bf16* base = z + (size_t)(p * N_SUPPORT) * D_FEAT;
    float part = 0.f;
    for (int j = t; j < D_FEAT; j += 256) {
        float m = 0.f;
#pragma unroll
        for (int ss = 0; ss < N_SUPPORT; ++ss) m += (float)base[(size_t)ss * D_FEAT + j];
        m *= (1.0f / N_SUPPORT);
        const float wj = wv[j];
        zpw[(size_t)p * D_FEAT + j] = (__bf16)(m * wj);
        part += m * m * wj;
    }
    part = waveReduceSum(part);
    const int lane = t & 63, wid = t >> 6;
    if (lane == 0) s_red[wid] = part;
    __syncthreads();
    if (t == 0) p2[p] = s_red[0] + s_red[1] + s_red[2] + s_red[3];
}

// ---------------- q2[i] = sum_j zq[i][j]^2 * w[j] ----------------
__global__ __launch_bounds__(256) void q2_kernel(const __bf16* __restrict__ z,
                                                 const float* __restrict__ wv,
                                                 float* __restrict__ q2)
{
    __shared__ float s_red[4];
    const int i = blockIdx.x;
    const int t = threadIdx.x;
    const __bf16* zq = z + (size_t)(NS + i) * D_FEAT;
    float part = 0.f;
    for (int j = t * 4; j < D_FEAT; j += 1024) {
        bf16x4 v4 = *(const bf16x4*)(zq + j);
        float4 w4 = *(const float4*)(wv + j);
        float a = (float)v4[0], b = (float)v4[1], c = (float)v4[2], d = (float)v4[3];
        part += a * a * w4.x + b * b * w4.y + c * c * w4.z + d * d * w4.w;
    }
    part = waveReduceSum(part);
    const int lane = t & 63, wid = t >> 6;
    if (lane == 0) s_red[wid] = part;
    __syncthreads();
    if (t == 0) q2[i] = s_red[0] + s_red[1] + s_red[2] + s_red[3];
}

__global__ void init_kernel(float* __restrict__ accum)
{
    if (threadIdx.x < 2) accum[threadIdx.x] = 0.f;
}

// ---------------- softmax/loss: one wave per query ----------------
__global__ __launch_bounds__(256) void loss_kernel(const float* __restrict__ cross,
                                                   const float* __restrict__ q2,
                                                   const float* __restrict__ p2,
                                                   float* __restrict__ accum)
{
    const int t = threadIdx.x;
    const int lane = t & 63, wid = t >> 6;
    const int i = blockIdx.x * 4 + wid;       // query 0..4095
    const float cr = cross[(size_t)i * 128 + lane];
    const float dist = q2[i] + p2[lane] - 2.0f * cr;
    const float neg = -dist;
    float m = neg;
    for (int off = 32; off > 0; off >>= 1) m = fmaxf(m, __shfl_xor(m, off, 64));
    float e = expf(neg - m);
    float ssum = e;
    for (int off = 32; off > 0; off >>= 1) ssum += __shfl_xor(ssum, off, 64);
    const float lse = m + logf(ssum);
    const int tcls = i >> 6;
    const float negt = __shfl(neg, tcls, 64);
    float v = dist; int bi = lane;
    for (int off = 32; off > 0; off >>= 1) {
        const float ov = __shfl_xor(v, off, 64);
        const int   oi = __shfl_xor(bi, off, 64);
        if (ov < v || (ov == v && oi < bi)) { v = ov; bi = oi; }
    }
    if (lane == 0) {
        atomicAdd(&accum[0], lse - negt);
        atomicAdd(&accum[1], (bi == tcls) ? 1.0f : 0.0f);
    }
}

__global__ void writeout_kernel(const float* __restrict__ accum, float* __restrict__ out)
{
    if (threadIdx.x == 0) {
        out[0] = accum[0] * (1.0f / NQ);
        out[1] = accum[1] * (1.0f / NQ);
    }
}

extern "C" void kernel_launch(void* const* d_in, const int* in_sizes, int n_in,
                              void* d_out, int out_size, void* d_ws, size_t ws_size,
                              hipStream_t stream)
{
    const float* xs      = (const float*)d_in[0];
    const float* xq      = (const float*)d_in[1];
    const float* W_share = (const float*)d_in[2];
    const float* b_share = (const float*)d_in[3];
    const float* W_att   = (const float*)d_in[4];
    const float* b_att   = (const float*)d_in[5];
    const float* W_fine  = (const float*)d_in[6];
    const float* b_fine  = (const float*)d_in[7];
    float* out = (float*)d_out;

    // workspace layout (bytes)
    char* ws = (char*)d_ws;
    __bf16* Xb   = (__bf16*)(ws);                      //  9,175,040 (freed after gemm1)
    float*  dists= (float*)(ws);                       //  alias: 4096*128*4 = 2,097,152
    float*  q2v  = (float*)(ws + 2097152);             //  alias: 16,384
    __bf16* Wsb  = (__bf16*)(ws + 9175040);            //  6,553,600
    __bf16* Wfb  = (__bf16*)(ws + 15728640);           // 20,480,000
    __bf16* Zsb  = (__bf16*)(ws + 36208640);           // 28,672,000
    __bf16* Zb   = (__bf16*)(ws + 64880640);           // 28,672,000
    __bf16* zpw  = (__bf16*)(ws + 93552640);           //    819,200
    float*  pm   = (float*)(ws + 94371840);
    float*  wv   = (float*)(ws + 94372352);
    float*  p2v  = (float*)(ws + 94385152);
    float*  zbias= (float*)(ws + 94385664);
    float*  accum= (float*)(ws + 94386176);

    init_kernel<<<1, 64, 0, stream>>>(accum);

    conv_x_kernel<<<(M_PAD * D_IN / 4 + 255) / 256, 256, 0, stream>>>(xs, xq, Xb);
    {
        dim3 grid(D_FEAT / 32, D_IN / 32);
        convT_kernel<<<grid, 256, 0, stream>>>(W_share, Wsb, D_IN, D_FEAT);
    }
    {
        dim3 grid(D_FEAT / 32, D_FEAT / 32);
        convT_kernel<<<grid, 256, 0, stream>>>(W_fine, Wfb, D_FEAT, D_FEAT);
    }

    // z_share = relu(x @ W_share^T' + b_share)
    gemm_bf16<<<(D_FEAT / 128) * (M_PAD / 128), 256, 0, stream>>>(
        Xb, Wsb, b_share, Zsb, nullptr, D_FEAT, D_IN, M_PAD, 1,
        D_FEAT / 128, M_PAD / 128);

    att1_kernel<<<C_CH, 256, 0, stream>>>(Zsb, pm);
    att2_kernel<<<1, C_CH, 0, stream>>>(pm, W_att, b_att, wv);

    // z = z_share @ W_fine^T' + b_fine
    gemm_bf16<<<(D_FEAT / 128) * (M_PAD / 128), 256, 0, stream>>>(
        Zsb, Wfb, b_fine, Zb, nullptr, D_FEAT, D_FEAT, M_ROWS, 0,
        D_FEAT / 128, M_PAD / 128);

    // prototypes (w folded in) + p2 + zero bias
    protow_kernel<<<128, 256, 0, stream>>>(Zb, wv, zpw, p2v, zbias);

    // q2 per query
    q2_kernel<<<NQ, 256, 0, stream>>>(Zb, wv, q2v);

    // cross = Zq @ zpw^T  (fp32 out, N=128 incl. zero pad cols)
    gemm_bf16<<<NQ / 128, 256, 0, stream>>>(
        Zb + (size_t)NS * D_FEAT, zpw, zbias, nullptr, dists, 128, D_FEAT, NQ, 0,
        1, NQ / 128);

    // per-query log-softmax + loss/acc
    loss_kernel<<<NQ / 4, 256, 0, stream>>>(dists, q2v, p2v, accum);

    writeout_kernel<<<1, 64, 0, stream>>>(accum, out);
}

// Round 4
// 484.813 us; speedup vs baseline: 1.2539x; 1.2539x over previous
//
#include <hip/hip_runtime.h>
#include <math.h>

// Problem constants
#define N_CLASS 64
#define N_SUPPORT 5
#define N_QUERY 64
#define D_IN 1024
#define C_CH 128
#define WIN 5
#define D_FEAT 3200            // C*WIN*WIN
#define NS 320                 // N_CLASS*N_SUPPORT
#define NQ 4096                // N_CLASS*N_QUERY
#define M_ROWS 4416            // NS+NQ
#define M_PAD 4480             // 35 * 128

typedef __bf16 bf16x8 __attribute__((ext_vector_type(8)));
typedef float floatx4 __attribute__((ext_vector_type(4)));
typedef __attribute__((address_space(1))) const void* gptr_t;
typedef __attribute__((address_space(3))) void* lptr_t;

__device__ __forceinline__ float waveReduceSum(float v) {
    for (int off = 32; off > 0; off >>= 1) v += __shfl_xor(v, off, 64);
    return v;
}

// ---------------- zero scratch accumulators (zp | G | cross | accum) ----------------
__global__ __launch_bounds__(256) void zero_kernel(float4* __restrict__ p, int n4)
{
    const int i = blockIdx.x * 256 + threadIdx.x;
    if (i < n4) p[i] = make_float4(0.f, 0.f, 0.f, 0.f);
}

// ---------------- convert x (xs|xq|zero-pad) -> bf16 [M_PAD][1024] ----------------
__global__ __launch_bounds__(256) void conv_x_kernel(const float* __restrict__ xs,
                                                     const float* __restrict__ xq,
                                                     __bf16* __restrict__ Xb)
{
    const int idx = blockIdx.x * 256 + threadIdx.x;
    const int e = idx * 4;
    if (e >= M_PAD * D_IN) return;
    const int row = e >> 10;
    const int col = e & 1023;
    float4 v = make_float4(0.f, 0.f, 0.f, 0.f);
    if (row < NS)            v = *(const float4*)(xs + (size_t)row * D_IN + col);
    else if (row < M_ROWS)   v = *(const float4*)(xq + (size_t)(row - NS) * D_IN + col);
    __bf16* o = Xb + (size_t)row * D_IN + col;
    o[0] = (__bf16)v.x; o[1] = (__bf16)v.y; o[2] = (__bf16)v.z; o[3] = (__bf16)v.w;
}

// ---------------- convert + transpose W [K][N] f32 -> Wt [N][K] bf16 ----------------
__global__ __launch_bounds__(256) void convT_kernel(const float* __restrict__ W,
                                                    __bf16* __restrict__ Wt,
                                                    int K, int N)
{
    __shared__ float tile[32][33];
    const int tx = threadIdx.x & 31;
    const int ty = threadIdx.x >> 5;
    const int n0 = blockIdx.x * 32;
    const int k0 = blockIdx.y * 32;
#pragma unroll
    for (int i = ty; i < 32; i += 8)
        tile[i][tx] = W[(size_t)(k0 + i) * N + n0 + tx];
    __syncthreads();
#pragma unroll
    for (int i = ty; i < 32; i += 8)
        Wt[(size_t)(n0 + i) * K + k0 + tx] = (__bf16)tile[tx][i];
}

// ---------------- MFMA GEMM: out = act(A @ Bt^T + bias), optional split-K atomic ----
// A [..][strideK] bf16, Bt [N][strideK] bf16. 128x128 tile, BK=32.
// grid = nbx*nby*nks (1D). XOR-swizzled LDS (conflict-free), global_load_lds staging.
__global__ __launch_bounds__(256) void gemm_bf16(const __bf16* __restrict__ A,
                                                 const __bf16* __restrict__ Bt,
                                                 const float* __restrict__ bias,
                                                 __bf16* __restrict__ out_bf,
                                                 float* __restrict__ out_f32,
                                                 int N, int strideK, int kIters,
                                                 int Mout, int relu, int atomic,
                                                 int nbx, int nby)
{
    __shared__ __align__(16) char smem[16384];   // sA [128][32] | sB [128][32] bf16

    // ---- block remap: ksplit + XCD-grouped columns ----
    int bx, by, ks;
    {
        const int nbxy = nbx * nby;
        ks = blockIdx.x / nbxy;
        const int b = blockIdx.x - ks * nbxy;
        const int fg = nbx >> 3;
        const int full = fg * 8 * nby;
        if (b < full) {
            const int g = b / (8 * nby);
            const int r = b - g * 8 * nby;
            bx = g * 8 + (r & 7);
            by = r >> 3;
        } else {
            const int rem = nbx - fg * 8;
            const int r = b - full;
            bx = fg * 8 + r % rem;
            by = r / rem;
        }
    }

    const int t    = threadIdx.x;
    const int lane = t & 63;
    const int w    = t >> 6;
    const int wm   = w >> 1;
    const int wn   = w & 1;
    const int bm   = by * 128;
    const int bn   = bx * 128;

    const int q    = lane >> 4;
    const int r16  = lane & 15;
    const int sw   = (r16 >> 1) & 3;
    const int cA   = (q ^ sw) * 8;

    const int srow   = w * 16 + (lane >> 2);
    const int sglob8 = (((lane & 3) ^ ((lane >> 3) & 3))) * 8;

    const int kBase = ks * kIters * 32;
    floatx4 acc[4][4] = {};

    for (int ki = 0; ki < kIters; ++ki) {
        const int k0 = kBase + ki * 32;
        __syncthreads();
#pragma unroll
        for (int j = 0; j < 2; ++j) {
            const __bf16* ga = A  + (size_t)(bm + j * 64 + srow) * strideK + k0 + sglob8;
            const __bf16* gb = Bt + (size_t)(bn + j * 64 + srow) * strideK + k0 + sglob8;
            char* la = smem +        (j * 256 + w * 64) * 16;
            char* lb = smem + 8192 + (j * 256 + w * 64) * 16;
            __builtin_amdgcn_global_load_lds((gptr_t)ga, (lptr_t)la, 16, 0, 0);
            __builtin_amdgcn_global_load_lds((gptr_t)gb, (lptr_t)lb, 16, 0, 0);
        }
        __syncthreads();

        const __bf16* sAe = (const __bf16*)smem;
        const __bf16* sBe = (const __bf16*)(smem + 8192);
        bf16x8 av[4], bv[4];
#pragma unroll
        for (int mi = 0; mi < 4; ++mi)
            av[mi] = *(const bf16x8*)(sAe + ((wm * 64 + mi * 16 + r16) * 32 + cA));
#pragma unroll
        for (int ni = 0; ni < 4; ++ni)
            bv[ni] = *(const bf16x8*)(sBe + ((wn * 64 + ni * 16 + r16) * 32 + cA));
#pragma unroll
        for (int mi = 0; mi < 4; ++mi)
#pragma unroll
            for (int ni = 0; ni < 4; ++ni)
                acc[mi][ni] = __builtin_amdgcn_mfma_f32_16x16x32_bf16(
                    av[mi], bv[ni], acc[mi][ni], 0, 0, 0);
    }

    // epilogue: C/D layout col=lane&15, row=(lane>>4)*4+reg
#pragma unroll
    for (int ni = 0; ni < 4; ++ni) {
        const int col = bn + wn * 64 + ni * 16 + r16;
        const float bcol = atomic ? 0.f : bias[col];
#pragma unroll
        for (int mi = 0; mi < 4; ++mi) {
#pragma unroll
            for (int reg = 0; reg < 4; ++reg) {
                const int row = bm + wm * 64 + mi * 16 + q * 4 + reg;
                if (row < Mout) {
                    if (atomic) {
                        atomicAdd(out_f32 + (size_t)row * N + col, acc[mi][ni][reg]);
                    } else {
                        float v = acc[mi][ni][reg] + bcol;
                        if (relu) v = fmaxf(v, 0.f);
                        if (out_f32) out_f32[(size_t)row * N + col] = v;
                        else         out_bf [(size_t)row * N + col] = (__bf16)v;
                    }
                }
            }
        }
    }
}

// ---------------- Attention stage 1: pooled mean over support rows ----------------
__global__ __launch_bounds__(256) void att1_kernel(const __bf16* __restrict__ z_share,
                                                   float* __restrict__ pm)
{
    __shared__ float s_red[4];
    const int c = blockIdx.x;
    const int t = threadIdx.x;
    float part = 0.f;
    for (int idx = t; idx < NS * 25; idx += 256) {
        const int r = idx / 25, p = idx % 25;
        part += (float)z_share[(size_t)r * D_FEAT + c * 25 + p];
    }
    part = waveReduceSum(part);
    const int lane = t & 63, wid = t >> 6;
    if (lane == 0) s_red[wid] = part;
    __syncthreads();
    if (t == 0)
        pm[c] = (s_red[0] + s_red[1] + s_red[2] + s_red[3]) * (1.0f / (NS * 25));
}

// ---------------- Attention stage 2: matvec + softmax -> w[3200] ----------------
__global__ __launch_bounds__(128) void att2_kernel(const float* __restrict__ pm,
                                                   const float* __restrict__ W_att,
                                                   const float* __restrict__ b_att,
                                                   float* __restrict__ wvec)
{
    __shared__ float s_att[C_CH];
    __shared__ float s_diag[C_CH];
    const int c = threadIdx.x;
    float acc = b_att[c];
    for (int k = 0; k < C_CH; ++k) acc += pm[k] * W_att[k * C_CH + c];
    s_att[c] = acc;
    __syncthreads();
    float m = -INFINITY;
    for (int k = 0; k < C_CH; ++k) m = fmaxf(m, s_att[k]);
    float s = 0.f;
    for (int k = 0; k < C_CH; ++k) s += expf(s_att[k] - m);
    s_diag[c] = expf(acc - m) / s * (float)C_CH;
    __syncthreads();
    for (int j = c; j < D_FEAT; j += C_CH) wvec[j] = s_diag[j / 25];
}

// ---------------- uT[k][p] = mean over supports of z_share[class p][k] --------------
__global__ __launch_bounds__(256) void ut_kernel(const __bf16* __restrict__ z_share,
                                                 float* __restrict__ uT)
{
    const int p = blockIdx.x;        // 0..63
    const int t = threadIdx.x;
    const __bf16* base = z_share + (size_t)(p * N_SUPPORT) * D_FEAT;
    for (int k = t; k < D_FEAT; k += 256) {
        float s = 0.f;
#pragma unroll
        for (int ss = 0; ss < N_SUPPORT; ++ss) s += (float)base[(size_t)ss * D_FEAT + k];
        uT[(size_t)k * N_CLASS + p] = s * (1.0f / N_SUPPORT);
    }
}

// ---------------- zp partial GEMM (rank-64) + fused Wf->bf16 natural copy -----------
// zp[p][j] += sum_{k in chunk} uT[k][p] * Wf[k][j]   (fp32 atomic)
// grid = 13 j-blocks x 25 k-blocks; also writes Wfb[k][j] = bf16(Wf[k][j]) once.
__global__ __launch_bounds__(256) void zpwf_kernel(const float* __restrict__ Wf,
                                                   const float* __restrict__ uT,
                                                   __bf16* __restrict__ Wfb,
                                                   float* __restrict__ zp)
{
    __shared__ float4 s_u[128 * 16];     // 128 k-rows x 64 p (as float4) = 32 KB
    const int jb = blockIdx.x % 13;
    const int kb = blockIdx.x / 13;      // 0..24
    const int t  = threadIdx.x;
    const int j  = jb * 256 + t;
    const int k0 = kb * 128;
    const bool jok = (j < D_FEAT);

    const float4* uT4 = (const float4*)(uT + (size_t)k0 * N_CLASS);
    for (int idx = t; idx < 128 * 16; idx += 256) s_u[idx] = uT4[idx];
    __syncthreads();

    float4 acc4[16] = {};
    for (int kk = 0; kk < 128; ++kk) {
        float wf = 0.f;
        if (jok) {
            wf = Wf[(size_t)(k0 + kk) * D_FEAT + j];
            Wfb[(size_t)(k0 + kk) * D_FEAT + j] = (__bf16)wf;
        }
        const float4* up4 = s_u + kk * 16;
#pragma unroll
        for (int c = 0; c < 16; ++c) {
            const float4 u = up4[c];
            acc4[c].x += wf * u.x;
            acc4[c].y += wf * u.y;
            acc4[c].z += wf * u.z;
            acc4[c].w += wf * u.w;
        }
    }
    if (jok) {
#pragma unroll
        for (int c = 0; c < 16; ++c) {
            atomicAdd(&zp[(size_t)(c * 4 + 0) * D_FEAT + j], acc4[c].x);
            atomicAdd(&zp[(size_t)(c * 4 + 1) * D_FEAT + j], acc4[c].y);
            atomicAdd(&zp[(size_t)(c * 4 + 2) * D_FEAT + j], acc4[c].z);
            atomicAdd(&zp[(size_t)(c * 4 + 3) * D_FEAT + j], acc4[c].w);
        }
    }
}

// ---------------- y = w*(zp+bf) bf16 [128 pad][3200]; p2; c ----------------
__global__ __launch_bounds__(256) void y_kernel(const float* __restrict__ zp,
                                                const float* __restrict__ wv,
                                                const float* __restrict__ bf,
                                                __bf16* __restrict__ y,
                                                float* __restrict__ p2,
                                                float* __restrict__ cvec)
{
    __shared__ float s_red2[8];
    const int p = blockIdx.x;        // 0..127
    const int t = threadIdx.x;
    if (p >= N_CLASS) {
        for (int j = t; j < D_FEAT; j += 256) y[(size_t)p * D_FEAT + j] = (__bf16)0.f;
        return;
    }
    float s2 = 0.f, sc = 0.f;
    for (int j = t; j < D_FEAT; j += 256) {
        const float zpf = zp[(size_t)p * D_FEAT + j] + bf[j];
        const float wj  = wv[j];
        y[(size_t)p * D_FEAT + j] = (__bf16)(wj * zpf);
        s2 += wj * zpf * zpf;
        sc += bf[j] * wj * zpf;
    }
    s2 = waveReduceSum(s2);
    sc = waveReduceSum(sc);
    const int lane = t & 63, wid = t >> 6;
    if (lane == 0) { s_red2[wid] = s2; s_red2[4 + wid] = sc; }
    __syncthreads();
    if (t == 0) {
        p2[p]   = s_red2[0] + s_red2[1] + s_red2[2] + s_red2[3];
        cvec[p] = s_red2[4] + s_red2[5] + s_red2[6] + s_red2[7];
    }
}

// ---------------- softmax/loss: one wave per query (q2 cancels; omitted) ------------
__global__ __launch_bounds__(256) void loss_kernel(const float* __restrict__ cross,
                                                   const float* __restrict__ p2,
                                                   const float* __restrict__ cvec,
                                                   float* __restrict__ accum)
{
    const int t = threadIdx.x;
    const int lane = t & 63, wid = t >> 6;
    const int i = blockIdx.x * 4 + wid;       // query 0..4095
    const float cr = cross[(size_t)i * 128 + lane];
    const float neg = 2.0f * (cr + cvec[lane]) - p2[lane];   // = -(dist) + q2 (const/row)
    float m = neg;
    for (int off = 32; off > 0; off >>= 1) m = fmaxf(m, __shfl_xor(m, off, 64));
    float e = expf(neg - m);
    float ssum = e;
    for (int off = 32; off > 0; off >>= 1) ssum += __shfl_xor(ssum, off, 64);
    const float lse = m + logf(ssum);
    const int tcls = i >> 6;
    const float negt = __shfl(neg, tcls, 64);
    float v = -neg; int bi = lane;            // argmin dist == argmax neg, first on tie
    for (int off = 32; off > 0; off >>= 1) {
        const float ov = __shfl_xor(v, off, 64);
        const int   oi = __shfl_xor(bi, off, 64);
        if (ov < v || (ov == v && oi < bi)) { v = ov; bi = oi; }
    }
    if (lane == 0) {
        atomicAdd(&accum[0], lse - negt);
        atomicAdd(&accum[1], (bi == tcls) ? 1.0f : 0.0f);
    }
}

__global__ void writeout_kernel(const float* __restrict__ accum, float* __restrict__ out)
{
    if (threadIdx.x == 0) {
        out[0] = accum[0] * (1.0f / NQ);
        out[1] = accum[1] * (1.0f / NQ);
    }
}

extern "C" void kernel_launch(void* const* d_in, const int* in_sizes, int n_in,
                              void* d_out, int out_size, void* d_ws, size_t ws_size,
                              hipStream_t stream)
{
    const float* xs      = (const float*)d_in[0];
    const float* xq      = (const float*)d_in[1];
    const float* W_share = (const float*)d_in[2];
    const float* b_share = (const float*)d_in[3];
    const float* W_att   = (const float*)d_in[4];
    const float* b_att   = (const float*)d_in[5];
    const float* W_fine  = (const float*)d_in[6];
    const float* b_fine  = (const float*)d_in[7];
    float* out = (float*)d_out;

    // workspace layout (bytes)
    char* ws = (char*)d_ws;
    __bf16* Xb   = (__bf16*)(ws);                      //  9,175,040
    __bf16* Wsb  = (__bf16*)(ws +  9175040);           //  6,553,600
    __bf16* Zsb  = (__bf16*)(ws + 15728640);           // 28,672,000
    __bf16* Wfb  = (__bf16*)(ws + 44400640);           // 20,480,000 (natural layout)
    float*  uT   = (float*) (ws + 64880640);           //    819,200  [3200][64]
    __bf16* yb   = (__bf16*)(ws + 65699840);           //    819,200  [128][3200]
    __bf16* Gt   = (__bf16*)(ws + 66519040);           //    819,200  [128][3200]
    // ---- zero-init region start ----
    float*  zp   = (float*) (ws + 67338240);           //    819,200  [64][3200]
    float*  G    = (float*) (ws + 68157440);           //  1,638,400  [3200][128]
    float*  cross= (float*) (ws + 69795840);           //  2,097,152  [4096][128]
    float*  accum= (float*) (ws + 71892992);           //          8
    // ---- zero-init region end (4,554,768 B) ----
    float*  pm   = (float*) (ws + 71893248);
    float*  wv   = (float*) (ws + 71893760);
    float*  p2v  = (float*) (ws + 71906560);
    float*  cvec = (float*) (ws + 71906816);

    const int n4 = 284673;   // 4,554,768 / 16
    zero_kernel<<<(n4 + 255) / 256, 256, 0, stream>>>((float4*)zp, n4);

    conv_x_kernel<<<(M_PAD * D_IN / 4 + 255) / 256, 256, 0, stream>>>(xs, xq, Xb);
    {
        dim3 grid(D_FEAT / 32, D_IN / 32);
        convT_kernel<<<grid, 256, 0, stream>>>(W_share, Wsb, D_IN, D_FEAT);
    }

    // z_share = relu(x @ W_share + b_share)  [4480][3200] bf16
    gemm_bf16<<<(D_FEAT / 128) * (M_PAD / 128), 256, 0, stream>>>(
        Xb, Wsb, b_share, Zsb, nullptr,
        D_FEAT, D_IN, D_IN / 32, M_PAD, 1, 0, D_FEAT / 128, M_PAD / 128);

    att1_kernel<<<C_CH, 256, 0, stream>>>(Zsb, pm);
    att2_kernel<<<1, C_CH, 0, stream>>>(pm, W_att, b_att, wv);

    // uT = support means (transposed), zp = u @ W_fine (+ fused Wf bf16 copy)
    ut_kernel<<<N_CLASS, 256, 0, stream>>>(Zsb, uT);
    zpwf_kernel<<<13 * 25, 256, 0, stream>>>(W_fine, uT, Wfb, zp);

    // y = w*(zp+b_fine), p2, c
    y_kernel<<<128, 256, 0, stream>>>(zp, wv, b_fine, yb, p2v, cvec);

    // G[k][p] = sum_j Wfb[k][j] * y[p][j]   (split-K 10, atomic fp32)
    gemm_bf16<<<1 * 25 * 10, 256, 0, stream>>>(
        Wfb, yb, nullptr, nullptr, G,
        128, D_FEAT, 10, D_FEAT, 0, 1, 1, 25);

    // Gt[p][k] = bf16(G[k][p])
    {
        dim3 grid(128 / 32, D_FEAT / 32);
        convT_kernel<<<grid, 256, 0, stream>>>(G, Gt, D_FEAT, 128);
    }

    // cross = zs_q @ Gt^T   (split-K 10, atomic fp32) [4096][128]
    gemm_bf16<<<1 * 32 * 10, 256, 0, stream>>>(
        Zsb + (size_t)NS * D_FEAT, Gt, nullptr, nullptr, cross,
        128, D_FEAT, 10, NQ, 0, 1, 1, 32);

    // per-query log-softmax + loss/acc (q2 omitted — cancels exactly)
    loss_kernel<<<NQ / 4, 256, 0, stream>>>(cross, p2v, cvec, accum);

    writeout_kernel<<<1, 64, 0, stream>>>(accum, out);
}

// Round 5
// 379.133 us; speedup vs baseline: 1.6034x; 1.2787x over previous
//
#include <hip/hip_runtime.h>
#include <math.h>

// Problem constants
#define N_CLASS 64
#define N_SUPPORT 5
#define N_QUERY 64
#define D_IN 1024
#define C_CH 128
#define WIN 5
#define D_FEAT 3200            // C*WIN*WIN
#define NS 320                 // N_CLASS*N_SUPPORT
#define NQ 4096                // N_CLASS*N_QUERY
#define M_ROWS 4416            // NS+NQ
#define M_PAD 4480             // 35 * 128

#define ZP_SLICE  (N_CLASS * D_FEAT)          // 204800
#define G_SLICE   (D_FEAT * 128)              // 409600
#define CR_SLICE  (NQ * 128)                  // 524288
#define NKS_G     10
#define NKS_CR    10
#define NKB_ZP    25
#define LOSS_BLKS (NQ / 4)                    // 1024

typedef __bf16 bf16x8 __attribute__((ext_vector_type(8)));
typedef float floatx4 __attribute__((ext_vector_type(4)));
typedef __attribute__((address_space(1))) const void* gptr_t;
typedef __attribute__((address_space(3))) void* lptr_t;

__device__ __forceinline__ float waveReduceSum(float v) {
    for (int off = 32; off > 0; off >>= 1) v += __shfl_xor(v, off, 64);
    return v;
}

// ---------------- convert x (xs|xq|zero-pad) -> bf16 [M_PAD][1024] ----------------
__global__ __launch_bounds__(256) void conv_x_kernel(const float* __restrict__ xs,
                                                     const float* __restrict__ xq,
                                                     __bf16* __restrict__ Xb)
{
    const int idx = blockIdx.x * 256 + threadIdx.x;
    const int e = idx * 4;
    if (e >= M_PAD * D_IN) return;
    const int row = e >> 10;
    const int col = e & 1023;
    float4 v = make_float4(0.f, 0.f, 0.f, 0.f);
    if (row < NS)            v = *(const float4*)(xs + (size_t)row * D_IN + col);
    else if (row < M_ROWS)   v = *(const float4*)(xq + (size_t)(row - NS) * D_IN + col);
    __bf16* o = Xb + (size_t)row * D_IN + col;
    o[0] = (__bf16)v.x; o[1] = (__bf16)v.y; o[2] = (__bf16)v.z; o[3] = (__bf16)v.w;
}

// ---------------- convert + transpose W [K][N] f32 -> Wt [N][K] bf16 ----------------
__global__ __launch_bounds__(256) void convT_kernel(const float* __restrict__ W,
                                                    __bf16* __restrict__ Wt,
                                                    int K, int N)
{
    __shared__ float tile[32][33];
    const int tx = threadIdx.x & 31;
    const int ty = threadIdx.x >> 5;
    const int n0 = blockIdx.x * 32;
    const int k0 = blockIdx.y * 32;
#pragma unroll
    for (int i = ty; i < 32; i += 8)
        tile[i][tx] = W[(size_t)(k0 + i) * N + n0 + tx];
    __syncthreads();
#pragma unroll
    for (int i = ty; i < 32; i += 8)
        Wt[(size_t)(n0 + i) * K + k0 + tx] = (__bf16)tile[tx][i];
}

// ---------------- transpose + slice-sum: Gt[n][k] = bf16(sum_s G_part[s][k][n]) -----
__global__ __launch_bounds__(256) void convT_sum_kernel(const float* __restrict__ Gp,
                                                        __bf16* __restrict__ Gt,
                                                        int K, int N,
                                                        int nslice, int slice)
{
    __shared__ float tile[32][33];
    const int tx = threadIdx.x & 31;
    const int ty = threadIdx.x >> 5;
    const int n0 = blockIdx.x * 32;
    const int k0 = blockIdx.y * 32;
#pragma unroll
    for (int i = ty; i < 32; i += 8) {
        float s = 0.f;
        for (int ss = 0; ss < nslice; ++ss)
            s += Gp[(size_t)ss * slice + (size_t)(k0 + i) * N + n0 + tx];
        tile[i][tx] = s;
    }
    __syncthreads();
#pragma unroll
    for (int i = ty; i < 32; i += 8)
        Gt[(size_t)(n0 + i) * K + k0 + tx] = (__bf16)tile[tx][i];
}

// ---------------- MFMA GEMM: out = act(A @ Bt^T + bias) or split-K partials --------
// A [..][strideK] bf16, Bt [N][strideK] bf16. 128x128 tile, BK=32.
// grid = nbx*nby*nks (1D). XOR-swizzled LDS (conflict-free), global_load_lds staging.
// sliceStride>0: plain-store fp32 partial at out_f32 + ks*sliceStride (no bias/relu).
__global__ __launch_bounds__(256) void gemm_bf16(const __bf16* __restrict__ A,
                                                 const __bf16* __restrict__ Bt,
                                                 const float* __restrict__ bias,
                                                 __bf16* __restrict__ out_bf,
                                                 float* __restrict__ out_f32,
                                                 int N, int strideK, int kIters,
                                                 int Mout, int relu, int sliceStride,
                                                 int nbx, int nby)
{
    __shared__ __align__(16) char smem[16384];   // sA [128][32] | sB [128][32] bf16

    // ---- block remap: ksplit + XCD-grouped columns ----
    int bx, by, ks;
    {
        const int nbxy = nbx * nby;
        ks = blockIdx.x / nbxy;
        const int b = blockIdx.x - ks * nbxy;
        const int fg = nbx >> 3;
        const int full = fg * 8 * nby;
        if (b < full) {
            const int g = b / (8 * nby);
            const int r = b - g * 8 * nby;
            bx = g * 8 + (r & 7);
            by = r >> 3;
        } else {
            const int rem = nbx - fg * 8;
            const int r = b - full;
            bx = fg * 8 + r % rem;
            by = r / rem;
        }
    }

    const int t    = threadIdx.x;
    const int lane = t & 63;
    const int w    = t >> 6;
    const int wm   = w >> 1;
    const int wn   = w & 1;
    const int bm   = by * 128;
    const int bn   = bx * 128;

    const int q    = lane >> 4;
    const int r16  = lane & 15;
    const int sw   = (r16 >> 1) & 3;
    const int cA   = (q ^ sw) * 8;

    const int srow   = w * 16 + (lane >> 2);
    const int sglob8 = (((lane & 3) ^ ((lane >> 3) & 3))) * 8;

    const int kBase = ks * kIters * 32;
    floatx4 acc[4][4] = {};

    for (int ki = 0; ki < kIters; ++ki) {
        const int k0 = kBase + ki * 32;
        __syncthreads();
#pragma unroll
        for (int j = 0; j < 2; ++j) {
            const __bf16* ga = A  + (size_t)(bm + j * 64 + srow) * strideK + k0 + sglob8;
            const __bf16* gb = Bt + (size_t)(bn + j * 64 + srow) * strideK + k0 + sglob8;
            char* la = smem +        (j * 256 + w * 64) * 16;
            char* lb = smem + 8192 + (j * 256 + w * 64) * 16;
            __builtin_amdgcn_global_load_lds((gptr_t)ga, (lptr_t)la, 16, 0, 0);
            __builtin_amdgcn_global_load_lds((gptr_t)gb, (lptr_t)lb, 16, 0, 0);
        }
        __syncthreads();

        const __bf16* sAe = (const __bf16*)smem;
        const __bf16* sBe = (const __bf16*)(smem + 8192);
        bf16x8 av[4], bv[4];
#pragma unroll
        for (int mi = 0; mi < 4; ++mi)
            av[mi] = *(const bf16x8*)(sAe + ((wm * 64 + mi * 16 + r16) * 32 + cA));
#pragma unroll
        for (int ni = 0; ni < 4; ++ni)
            bv[ni] = *(const bf16x8*)(sBe + ((wn * 64 + ni * 16 + r16) * 32 + cA));
#pragma unroll
        for (int mi = 0; mi < 4; ++mi)
#pragma unroll
            for (int ni = 0; ni < 4; ++ni)
                acc[mi][ni] = __builtin_amdgcn_mfma_f32_16x16x32_bf16(
                    av[mi], bv[ni], acc[mi][ni], 0, 0, 0);
    }

    // epilogue: C/D layout col=lane&15, row=(lane>>4)*4+reg
#pragma unroll
    for (int ni = 0; ni < 4; ++ni) {
        const int col = bn + wn * 64 + ni * 16 + r16;
        const float bcol = sliceStride ? 0.f : bias[col];
#pragma unroll
        for (int mi = 0; mi < 4; ++mi) {
#pragma unroll
            for (int reg = 0; reg < 4; ++reg) {
                const int row = bm + wm * 64 + mi * 16 + q * 4 + reg;
                if (row < Mout) {
                    if (sliceStride) {
                        out_f32[(size_t)ks * sliceStride + (size_t)row * N + col] =
                            acc[mi][ni][reg];
                    } else {
                        float v = acc[mi][ni][reg] + bcol;
                        if (relu) v = fmaxf(v, 0.f);
                        if (out_f32) out_f32[(size_t)row * N + col] = v;
                        else         out_bf [(size_t)row * N + col] = (__bf16)v;
                    }
                }
            }
        }
    }
}

// ---------------- Attention stage 1: pooled mean over support rows ----------------
__global__ __launch_bounds__(256) void att1_kernel(const __bf16* __restrict__ z_share,
                                                   float* __restrict__ pm)
{
    __shared__ float s_red[4];
    const int c = blockIdx.x;
    const int t = threadIdx.x;
    float part = 0.f;
    for (int idx = t; idx < NS * 25; idx += 256) {
        const int r = idx / 25, p = idx % 25;
        part += (float)z_share[(size_t)r * D_FEAT + c * 25 + p];
    }
    part = waveReduceSum(part);
    const int lane = t & 63, wid = t >> 6;
    if (lane == 0) s_red[wid] = part;
    __syncthreads();
    if (t == 0)
        pm[c] = (s_red[0] + s_red[1] + s_red[2] + s_red[3]) * (1.0f / (NS * 25));
}

// ---------------- Attention stage 2: matvec + softmax -> w[3200] ----------------
__global__ __launch_bounds__(128) void att2_kernel(const float* __restrict__ pm,
                                                   const float* __restrict__ W_att,
                                                   const float* __restrict__ b_att,
                                                   float* __restrict__ wvec)
{
    __shared__ float s_att[C_CH];
    __shared__ float s_diag[C_CH];
    const int c = threadIdx.x;
    float acc = b_att[c];
    for (int k = 0; k < C_CH; ++k) acc += pm[k] * W_att[k * C_CH + c];
    s_att[c] = acc;
    __syncthreads();
    float m = -INFINITY;
    for (int k = 0; k < C_CH; ++k) m = fmaxf(m, s_att[k]);
    float s = 0.f;
    for (int k = 0; k < C_CH; ++k) s += expf(s_att[k] - m);
    s_diag[c] = expf(acc - m) / s * (float)C_CH;
    __syncthreads();
    for (int j = c; j < D_FEAT; j += C_CH) wvec[j] = s_diag[j / 25];
}

// ---------------- uT[k][p] = mean over supports of z_share[class p][k] --------------
__global__ __launch_bounds__(256) void ut_kernel(const __bf16* __restrict__ z_share,
                                                 float* __restrict__ uT)
{
    const int p = blockIdx.x;        // 0..63
    const int t = threadIdx.x;
    const __bf16* base = z_share + (size_t)(p * N_SUPPORT) * D_FEAT;
    for (int k = t; k < D_FEAT; k += 256) {
        float s = 0.f;
#pragma unroll
        for (int ss = 0; ss < N_SUPPORT; ++ss) s += (float)base[(size_t)ss * D_FEAT + k];
        uT[(size_t)k * N_CLASS + p] = s * (1.0f / N_SUPPORT);
    }
}

// ---------------- zp partial (rank-64) + fused Wf->bf16 natural copy ----------------
// zp_part[kb][p][j] = sum_{k in chunk kb} uT[k][p] * Wf[k][j]   (plain stores)
__global__ __launch_bounds__(256) void zpwf_kernel(const float* __restrict__ Wf,
                                                   const float* __restrict__ uT,
                                                   __bf16* __restrict__ Wfb,
                                                   float* __restrict__ zp_part)
{
    __shared__ float4 s_u[128 * 16];     // 128 k-rows x 64 p (as float4) = 32 KB
    const int jb = blockIdx.x % 13;
    const int kb = blockIdx.x / 13;      // 0..24
    const int t  = threadIdx.x;
    const int j  = jb * 256 + t;
    const int k0 = kb * 128;
    const bool jok = (j < D_FEAT);

    const float4* uT4 = (const float4*)(uT + (size_t)k0 * N_CLASS);
    for (int idx = t; idx < 128 * 16; idx += 256) s_u[idx] = uT4[idx];
    __syncthreads();

    float4 acc4[16] = {};
    for (int kk = 0; kk < 128; ++kk) {
        float wf = 0.f;
        if (jok) {
            wf = Wf[(size_t)(k0 + kk) * D_FEAT + j];
            Wfb[(size_t)(k0 + kk) * D_FEAT + j] = (__bf16)wf;
        }
        const float4* up4 = s_u + kk * 16;
#pragma unroll
        for (int c = 0; c < 16; ++c) {
            const float4 u = up4[c];
            acc4[c].x += wf * u.x;
            acc4[c].y += wf * u.y;
            acc4[c].z += wf * u.z;
            acc4[c].w += wf * u.w;
        }
    }
    if (jok) {
        float* dst = zp_part + (size_t)kb * ZP_SLICE;
#pragma unroll
        for (int c = 0; c < 16; ++c) {
            dst[(size_t)(c * 4 + 0) * D_FEAT + j] = acc4[c].x;
            dst[(size_t)(c * 4 + 1) * D_FEAT + j] = acc4[c].y;
            dst[(size_t)(c * 4 + 2) * D_FEAT + j] = acc4[c].z;
            dst[(size_t)(c * 4 + 3) * D_FEAT + j] = acc4[c].w;
        }
    }
}

// ---------------- y = w*(sum zp_part + bf) bf16 [128 pad][3200]; p2; c --------------
__global__ __launch_bounds__(256) void y_kernel(const float* __restrict__ zp_part,
                                                const float* __restrict__ wv,
                                                const float* __restrict__ bf,
                                                __bf16* __restrict__ y,
                                                float* __restrict__ p2,
                                                float* __restrict__ cvec)
{
    __shared__ float s_red2[8];
    const int p = blockIdx.x;        // 0..127
    const int t = threadIdx.x;
    if (p >= N_CLASS) {
        for (int j = t; j < D_FEAT; j += 256) y[(size_t)p * D_FEAT + j] = (__bf16)0.f;
        return;
    }
    float s2 = 0.f, sc = 0.f;
    for (int j = t; j < D_FEAT; j += 256) {
        float zpf = bf[j];
        for (int ss = 0; ss < NKB_ZP; ++ss)
            zpf += zp_part[(size_t)ss * ZP_SLICE + (size_t)p * D_FEAT + j];
        const float wj = wv[j];
        y[(size_t)p * D_FEAT + j] = (__bf16)(wj * zpf);
        s2 += wj * zpf * zpf;
        sc += bf[j] * wj * zpf;
    }
    s2 = waveReduceSum(s2);
    sc = waveReduceSum(sc);
    const int lane = t & 63, wid = t >> 6;
    if (lane == 0) { s_red2[wid] = s2; s_red2[4 + wid] = sc; }
    __syncthreads();
    if (t == 0) {
        p2[p]   = s_red2[0] + s_red2[1] + s_red2[2] + s_red2[3];
        cvec[p] = s_red2[4] + s_red2[5] + s_red2[6] + s_red2[7];
    }
}

// ---------------- softmax/loss: one wave per query, block partials (no atomics) -----
__global__ __launch_bounds__(256) void loss_kernel(const float* __restrict__ cross_part,
                                                   const float* __restrict__ p2,
                                                   const float* __restrict__ cvec,
                                                   float* __restrict__ lpart)
{
    __shared__ float s_l[4], s_a[4];
    const int t = threadIdx.x;
    const int lane = t & 63, wid = t >> 6;
    const int i = blockIdx.x * 4 + wid;       // query 0..4095
    float cr = 0.f;
#pragma unroll
    for (int ss = 0; ss < NKS_CR; ++ss)
        cr += cross_part[(size_t)ss * CR_SLICE + (size_t)i * 128 + lane];
    const float neg = 2.0f * (cr + cvec[lane]) - p2[lane];   // -(dist) + const/row
    float m = neg;
    for (int off = 32; off > 0; off >>= 1) m = fmaxf(m, __shfl_xor(m, off, 64));
    float e = expf(neg - m);
    float ssum = e;
    for (int off = 32; off > 0; off >>= 1) ssum += __shfl_xor(ssum, off, 64);
    const float lse = m + logf(ssum);
    const int tcls = i >> 6;
    const float negt = __shfl(neg, tcls, 64);
    float v = -neg; int bi = lane;            // argmin dist == argmax neg, first on tie
    for (int off = 32; off > 0; off >>= 1) {
        const float ov = __shfl_xor(v, off, 64);
        const int   oi = __shfl_xor(bi, off, 64);
        if (ov < v || (ov == v && oi < bi)) { v = ov; bi = oi; }
    }
    if (lane == 0) { s_l[wid] = lse - negt; s_a[wid] = (bi == tcls) ? 1.0f : 0.0f; }
    __syncthreads();
    if (t == 0) {
        lpart[blockIdx.x]             = s_l[0] + s_l[1] + s_l[2] + s_l[3];
        lpart[LOSS_BLKS + blockIdx.x] = s_a[0] + s_a[1] + s_a[2] + s_a[3];
    }
}

__global__ __launch_bounds__(256) void writeout_kernel(const float* __restrict__ lpart,
                                                       float* __restrict__ out)
{
    __shared__ float s_red2[8];
    const int t = threadIdx.x;
    float l = 0.f, a = 0.f;
    for (int k = t; k < LOSS_BLKS; k += 256) {
        l += lpart[k];
        a += lpart[LOSS_BLKS + k];
    }
    l = waveReduceSum(l);
    a = waveReduceSum(a);
    const int lane = t & 63, wid = t >> 6;
    if (lane == 0) { s_red2[wid] = l; s_red2[4 + wid] = a; }
    __syncthreads();
    if (t == 0) {
        out[0] = (s_red2[0] + s_red2[1] + s_red2[2] + s_red2[3]) * (1.0f / NQ);
        out[1] = (s_red2[4] + s_red2[5] + s_red2[6] + s_red2[7]) * (1.0f / NQ);
    }
}

extern "C" void kernel_launch(void* const* d_in, const int* in_sizes, int n_in,
                              void* d_out, int out_size, void* d_ws, size_t ws_size,
                              hipStream_t stream)
{
    const float* xs      = (const float*)d_in[0];
    const float* xq      = (const float*)d_in[1];
    const float* W_share = (const float*)d_in[2];
    const float* b_share = (const float*)d_in[3];
    const float* W_att   = (const float*)d_in[4];
    const float* b_att   = (const float*)d_in[5];
    const float* W_fine  = (const float*)d_in[6];
    const float* b_fine  = (const float*)d_in[7];
    float* out = (float*)d_out;

    // workspace layout (bytes); arena holds zp_part -> G_part -> cross_part
    // (sequentially dead, stream-ordered)
    char* ws = (char*)d_ws;
    __bf16* Xb      = (__bf16*)(ws);                   //  9,175,040
    __bf16* Wsb     = (__bf16*)(ws +  9175040);        //  6,553,600
    __bf16* Zsb     = (__bf16*)(ws + 15728640);        // 28,672,000
    __bf16* Wfb     = (__bf16*)(ws + 44400640);        // 20,480,000 (natural layout)
    float*  arena   = (float*) (ws + 64880640);        // 20,971,520
    float*  zp_part = arena;                           // 25*204800*4 = 20,480,000
    float*  G_part  = arena;                           // 10*409600*4 = 16,384,000
    float*  cr_part = arena;                           // 10*524288*4 = 20,971,520
    float*  uT      = (float*) (ws + 85852160);        //    819,200  [3200][64]
    __bf16* yb      = (__bf16*)(ws + 86671360);        //    819,200  [128][3200]
    __bf16* Gt      = (__bf16*)(ws + 87490560);        //    819,200  [128][3200]
    float*  pm      = (float*) (ws + 88309760);
    float*  wv      = (float*) (ws + 88310272);
    float*  p2v     = (float*) (ws + 88323072);
    float*  cvec    = (float*) (ws + 88323584);
    float*  lpart   = (float*) (ws + 88324096);        //      8,192

    conv_x_kernel<<<(M_PAD * D_IN / 4 + 255) / 256, 256, 0, stream>>>(xs, xq, Xb);
    {
        dim3 grid(D_FEAT / 32, D_IN / 32);
        convT_kernel<<<grid, 256, 0, stream>>>(W_share, Wsb, D_IN, D_FEAT);
    }

    // z_share = relu(x @ W_share + b_share)  [4480][3200] bf16
    gemm_bf16<<<(D_FEAT / 128) * (M_PAD / 128), 256, 0, stream>>>(
        Xb, Wsb, b_share, Zsb, nullptr,
        D_FEAT, D_IN, D_IN / 32, M_PAD, 1, 0, D_FEAT / 128, M_PAD / 128);

    att1_kernel<<<C_CH, 256, 0, stream>>>(Zsb, pm);
    att2_kernel<<<1, C_CH, 0, stream>>>(pm, W_att, b_att, wv);

    // uT = support means (transposed); zp partials (+ fused Wf bf16 copy)
    ut_kernel<<<N_CLASS, 256, 0, stream>>>(Zsb, uT);
    zpwf_kernel<<<13 * NKB_ZP, 256, 0, stream>>>(W_fine, uT, Wfb, zp_part);

    // y = w*(zp+b_fine), p2, c   (sums the 25 zp partials)
    y_kernel<<<128, 256, 0, stream>>>(zp_part, wv, b_fine, yb, p2v, cvec);

    // G_part[ks][k][p] = partial sum_j Wfb[k][j] * y[p][j]   (plain stores)
    gemm_bf16<<<1 * 25 * NKS_G, 256, 0, stream>>>(
        Wfb, yb, nullptr, nullptr, G_part,
        128, D_FEAT, D_FEAT / 32 / NKS_G, D_FEAT, 0, G_SLICE, 1, 25);

    // Gt[p][k] = bf16(sum_ks G_part[ks][k][p])
    {
        dim3 grid(128 / 32, D_FEAT / 32);
        convT_sum_kernel<<<grid, 256, 0, stream>>>(G_part, Gt, D_FEAT, 128,
                                                   NKS_G, G_SLICE);
    }

    // cross_part[ks][i][p] = partial zs_q @ Gt^T   (plain stores) [4096][128]
    gemm_bf16<<<1 * 32 * NKS_CR, 256, 0, stream>>>(
        Zsb + (size_t)NS * D_FEAT, Gt, nullptr, nullptr, cr_part,
        128, D_FEAT, D_FEAT / 32 / NKS_CR, NQ, 0, CR_SLICE, 1, 32);

    // per-query log-softmax + loss/acc -> block partials (no atomics)
    loss_kernel<<<LOSS_BLKS, 256, 0, stream>>>(cr_part, p2v, cvec, lpart);

    writeout_kernel<<<1, 256, 0, stream>>>(lpart, out);
}

// Round 6
// 305.517 us; speedup vs baseline: 1.9898x; 1.2410x over previous
//
#include <hip/hip_runtime.h>
#include <math.h>

// Problem constants
#define N_CLASS 64
#define N_SUPPORT 5
#define N_QUERY 64
#define D_IN 1024
#define C_CH 128
#define WIN 5
#define D_FEAT 3200            // C*WIN*WIN
#define NS 320                 // N_CLASS*N_SUPPORT
#define NQ 4096                // N_CLASS*N_QUERY
#define M_ROWS 4416            // NS+NQ
#define M_PAD 4480             // 35 * 128

#define ZP_SLICE  (N_CLASS * D_FEAT)          // 204800
#define GT_SLICE  (128 * D_FEAT)              // 409600
#define CR_SLICE  (NQ * 128)                  // 524288
#define NKS       10                          // split-K slices
#define LOSS_BLKS (NQ / 4)                    // 1024

typedef __bf16 bf16x8 __attribute__((ext_vector_type(8)));
typedef __bf16 bf16x4 __attribute__((ext_vector_type(4)));
typedef float floatx4 __attribute__((ext_vector_type(4)));
typedef __attribute__((address_space(1))) const void* gptr_t;
typedef __attribute__((address_space(3))) void* lptr_t;

__device__ __forceinline__ float waveReduceSum(float v) {
    for (int off = 32; off > 0; off >>= 1) v += __shfl_xor(v, off, 64);
    return v;
}

// ---------------- convert x (xs|xq|zero-pad) -> bf16 [M_PAD][1024] ----------------
__global__ __launch_bounds__(256) void conv_x_kernel(const float* __restrict__ xs,
                                                     const float* __restrict__ xq,
                                                     __bf16* __restrict__ Xb)
{
    const int idx = blockIdx.x * 256 + threadIdx.x;
    const int e = idx * 4;
    if (e >= M_PAD * D_IN) return;
    const int row = e >> 10;
    const int col = e & 1023;
    float4 v = make_float4(0.f, 0.f, 0.f, 0.f);
    if (row < NS)            v = *(const float4*)(xs + (size_t)row * D_IN + col);
    else if (row < M_ROWS)   v = *(const float4*)(xq + (size_t)(row - NS) * D_IN + col);
    __bf16* o = Xb + (size_t)row * D_IN + col;
    o[0] = (__bf16)v.x; o[1] = (__bf16)v.y; o[2] = (__bf16)v.z; o[3] = (__bf16)v.w;
}

// ---------------- convert + transpose W [K][N] f32 -> Wt [N][K] bf16 ----------------
__global__ __launch_bounds__(256) void convT_kernel(const float* __restrict__ W,
                                                    __bf16* __restrict__ Wt,
                                                    int K, int N)
{
    __shared__ float tile[32][33];
    const int tx = threadIdx.x & 31;
    const int ty = threadIdx.x >> 5;
    const int n0 = blockIdx.x * 32;
    const int k0 = blockIdx.y * 32;
#pragma unroll
    for (int i = ty; i < 32; i += 8)
        tile[i][tx] = W[(size_t)(k0 + i) * N + n0 + tx];
    __syncthreads();
#pragma unroll
    for (int i = ty; i < 32; i += 8)
        Wt[(size_t)(n0 + i) * K + k0 + tx] = (__bf16)tile[tx][i];
}

// ---------- dual-layout convert: Wn[k][j]=bf16(W), Wt[j][k]=bf16(W) ----------
__global__ __launch_bounds__(256) void convT2_kernel(const float* __restrict__ W,
                                                     __bf16* __restrict__ Wn,
                                                     __bf16* __restrict__ Wt,
                                                     int K, int N)
{
    __shared__ float tile[32][33];
    const int tx = threadIdx.x & 31;
    const int ty = threadIdx.x >> 5;
    const int n0 = blockIdx.x * 32;
    const int k0 = blockIdx.y * 32;
#pragma unroll
    for (int i = ty; i < 32; i += 8) {
        const float v = W[(size_t)(k0 + i) * N + n0 + tx];
        Wn[(size_t)(k0 + i) * N + n0 + tx] = (__bf16)v;
        tile[i][tx] = v;
    }
    __syncthreads();
#pragma unroll
    for (int i = ty; i < 32; i += 8)
        Wt[(size_t)(n0 + i) * K + k0 + tx] = (__bf16)tile[tx][i];
}

// ---------------- MFMA GEMM: out = act(A @ Bt^T + bias) or split-K partials --------
// A [..][strideK] bf16, Bt [N][strideK] bf16. 128x128 tile, BK=32.
// grid = nbx*nby*nks (1D). XOR-swizzled LDS (conflict-free), global_load_lds staging.
// sliceStride>0: plain-store fp32 partial at out_f32 + ks*sliceStride (no bias/relu).
__global__ __launch_bounds__(256) void gemm_bf16(const __bf16* __restrict__ A,
                                                 const __bf16* __restrict__ Bt,
                                                 const float* __restrict__ bias,
                                                 __bf16* __restrict__ out_bf,
                                                 float* __restrict__ out_f32,
                                                 int N, int strideK, int kIters,
                                                 int Mout, int relu, int sliceStride,
                                                 int nbx, int nby)
{
    __shared__ __align__(16) char smem[16384];   // sA [128][32] | sB [128][32] bf16

    // ---- block remap: ksplit + XCD-grouped columns ----
    int bx, by, ks;
    {
        const int nbxy = nbx * nby;
        ks = blockIdx.x / nbxy;
        const int b = blockIdx.x - ks * nbxy;
        const int fg = nbx >> 3;
        const int full = fg * 8 * nby;
        if (b < full) {
            const int g = b / (8 * nby);
            const int r = b - g * 8 * nby;
            bx = g * 8 + (r & 7);
            by = r >> 3;
        } else {
            const int rem = nbx - fg * 8;
            const int r = b - full;
            bx = fg * 8 + r % rem;
            by = r / rem;
        }
    }

    const int t    = threadIdx.x;
    const int lane = t & 63;
    const int w    = t >> 6;
    const int wm   = w >> 1;
    const int wn   = w & 1;
    const int bm   = by * 128;
    const int bn   = bx * 128;

    const int q    = lane >> 4;
    const int r16  = lane & 15;
    const int sw   = (r16 >> 1) & 3;
    const int cA   = (q ^ sw) * 8;

    const int srow   = w * 16 + (lane >> 2);
    const int sglob8 = (((lane & 3) ^ ((lane >> 3) & 3))) * 8;

    const int kBase = ks * kIters * 32;
    floatx4 acc[4][4] = {};

    for (int ki = 0; ki < kIters; ++ki) {
        const int k0 = kBase + ki * 32;
        __syncthreads();
#pragma unroll
        for (int j = 0; j < 2; ++j) {
            const __bf16* ga = A  + (size_t)(bm + j * 64 + srow) * strideK + k0 + sglob8;
            const __bf16* gb = Bt + (size_t)(bn + j * 64 + srow) * strideK + k0 + sglob8;
            char* la = smem +        (j * 256 + w * 64) * 16;
            char* lb = smem + 8192 + (j * 256 + w * 64) * 16;
            __builtin_amdgcn_global_load_lds((gptr_t)ga, (lptr_t)la, 16, 0, 0);
            __builtin_amdgcn_global_load_lds((gptr_t)gb, (lptr_t)lb, 16, 0, 0);
        }
        __syncthreads();

        const __bf16* sAe = (const __bf16*)smem;
        const __bf16* sBe = (const __bf16*)(smem + 8192);
        bf16x8 av[4], bv[4];
#pragma unroll
        for (int mi = 0; mi < 4; ++mi)
            av[mi] = *(const bf16x8*)(sAe + ((wm * 64 + mi * 16 + r16) * 32 + cA));
#pragma unroll
        for (int ni = 0; ni < 4; ++ni)
            bv[ni] = *(const bf16x8*)(sBe + ((wn * 64 + ni * 16 + r16) * 32 + cA));
#pragma unroll
        for (int mi = 0; mi < 4; ++mi)
#pragma unroll
            for (int ni = 0; ni < 4; ++ni)
                acc[mi][ni] = __builtin_amdgcn_mfma_f32_16x16x32_bf16(
                    av[mi], bv[ni], acc[mi][ni], 0, 0, 0);
    }

    // epilogue: C/D layout col=lane&15, row=(lane>>4)*4+reg
#pragma unroll
    for (int ni = 0; ni < 4; ++ni) {
        const int col = bn + wn * 64 + ni * 16 + r16;
        const float bcol = sliceStride ? 0.f : bias[col];
#pragma unroll
        for (int mi = 0; mi < 4; ++mi) {
#pragma unroll
            for (int reg = 0; reg < 4; ++reg) {
                const int row = bm + wm * 64 + mi * 16 + q * 4 + reg;
                if (row < Mout) {
                    if (sliceStride) {
                        out_f32[(size_t)ks * sliceStride + (size_t)row * N + col] =
                            acc[mi][ni][reg];
                    } else {
                        float v = acc[mi][ni][reg] + bcol;
                        if (relu) v = fmaxf(v, 0.f);
                        if (out_f32) out_f32[(size_t)row * N + col] = v;
                        else         out_bf [(size_t)row * N + col] = (__bf16)v;
                    }
                }
            }
        }
    }
}

// ---------------- Attention stage 1: pooled mean over support rows ----------------
__global__ __launch_bounds__(256) void att1_kernel(const __bf16* __restrict__ z_share,
                                                   float* __restrict__ pm)
{
    __shared__ float s_red[4];
    const int c = blockIdx.x;
    const int t = threadIdx.x;
    float part = 0.f;
    for (int idx = t; idx < NS * 25; idx += 256) {
        const int r = idx / 25, p = idx % 25;
        part += (float)z_share[(size_t)r * D_FEAT + c * 25 + p];
    }
    part = waveReduceSum(part);
    const int lane = t & 63, wid = t >> 6;
    if (lane == 0) s_red[wid] = part;
    __syncthreads();
    if (t == 0)
        pm[c] = (s_red[0] + s_red[1] + s_red[2] + s_red[3]) * (1.0f / (NS * 25));
}

// ---------------- Attention stage 2: matvec + softmax -> w[3200] ----------------
__global__ __launch_bounds__(128) void att2_kernel(const float* __restrict__ pm,
                                                   const float* __restrict__ W_att,
                                                   const float* __restrict__ b_att,
                                                   float* __restrict__ wvec)
{
    __shared__ float s_att[C_CH];
    __shared__ float s_diag[C_CH];
    const int c = threadIdx.x;
    float acc = b_att[c];
    for (int k = 0; k < C_CH; ++k) acc += pm[k] * W_att[k * C_CH + c];
    s_att[c] = acc;
    __syncthreads();
    float m = -INFINITY;
    for (int k = 0; k < C_CH; ++k) m = fmaxf(m, s_att[k]);
    float s = 0.f;
    for (int k = 0; k < C_CH; ++k) s += expf(s_att[k] - m);
    s_diag[c] = expf(acc - m) / s * (float)C_CH;
    __syncthreads();
    for (int j = c; j < D_FEAT; j += C_CH) wvec[j] = s_diag[j / 25];
}

// ------- u[p][k] = mean over supports of z_share[class p][k], bf16, pad rows 0 ------
__global__ __launch_bounds__(256) void ut_kernel(const __bf16* __restrict__ z_share,
                                                 __bf16* __restrict__ u)
{
    const int p = blockIdx.x;        // 0..127
    const int t = threadIdx.x;
    if (p >= N_CLASS) {
        for (int k = t; k < D_FEAT; k += 256) u[(size_t)p * D_FEAT + k] = (__bf16)0.f;
        return;
    }
    const __bf16* base = z_share + (size_t)(p * N_SUPPORT) * D_FEAT;
    for (int k = t; k < D_FEAT; k += 256) {
        float s = 0.f;
#pragma unroll
        for (int ss = 0; ss < N_SUPPORT; ++ss) s += (float)base[(size_t)ss * D_FEAT + k];
        u[(size_t)p * D_FEAT + k] = (__bf16)(s * (1.0f / N_SUPPORT));
    }
}

// ---------------- y = w*(sum zp_part + bf) bf16 [128 pad][3200]; p2; c --------------
__global__ __launch_bounds__(256) void y_kernel(const float* __restrict__ zp_part,
                                                const float* __restrict__ wv,
                                                const float* __restrict__ bf,
                                                __bf16* __restrict__ y,
                                                float* __restrict__ p2,
                                                float* __restrict__ cvec)
{
    __shared__ float s_red2[8];
    const int p = blockIdx.x;        // 0..127
    const int t = threadIdx.x;
    if (p >= N_CLASS) {
        for (int j = t; j < D_FEAT; j += 256) y[(size_t)p * D_FEAT + j] = (__bf16)0.f;
        return;
    }
    float s2 = 0.f, sc = 0.f;
    for (int j = t; j < D_FEAT; j += 256) {
        float zpf = bf[j];
#pragma unroll
        for (int ss = 0; ss < NKS; ++ss)
            zpf += zp_part[(size_t)ss * ZP_SLICE + (size_t)p * D_FEAT + j];
        const float wj = wv[j];
        y[(size_t)p * D_FEAT + j] = (__bf16)(wj * zpf);
        s2 += wj * zpf * zpf;
        sc += bf[j] * wj * zpf;
    }
    s2 = waveReduceSum(s2);
    sc = waveReduceSum(sc);
    const int lane = t & 63, wid = t >> 6;
    if (lane == 0) { s_red2[wid] = s2; s_red2[4 + wid] = sc; }
    __syncthreads();
    if (t == 0) {
        p2[p]   = s_red2[0] + s_red2[1] + s_red2[2] + s_red2[3];
        cvec[p] = s_red2[4] + s_red2[5] + s_red2[6] + s_red2[7];
    }
}

// ---------------- Gt[p][k] bf16 = sum of 10 fp32 slices [128][3200] ----------------
__global__ __launch_bounds__(256) void gtsum_kernel(const float* __restrict__ gp,
                                                    __bf16* __restrict__ Gt)
{
    const int i4 = blockIdx.x * 256 + threadIdx.x;     // over 409600/4
    if (i4 >= GT_SLICE / 4) return;
    float4 s = make_float4(0.f, 0.f, 0.f, 0.f);
#pragma unroll
    for (int ss = 0; ss < NKS; ++ss) {
        const float4 v = *(const float4*)(gp + (size_t)ss * GT_SLICE + i4 * 4);
        s.x += v.x; s.y += v.y; s.z += v.z; s.w += v.w;
    }
    bf16x4 o = { (__bf16)s.x, (__bf16)s.y, (__bf16)s.z, (__bf16)s.w };
    *(bf16x4*)(Gt + (size_t)i4 * 4) = o;
}

// ---------------- softmax/loss: one wave per query, block partials (no atomics) -----
__global__ __launch_bounds__(256) void loss_kernel(const float* __restrict__ cross_part,
                                                   const float* __restrict__ p2,
                                                   const float* __restrict__ cvec,
                                                   float* __restrict__ lpart)
{
    __shared__ float s_l[4], s_a[4];
    const int t = threadIdx.x;
    const int lane = t & 63, wid = t >> 6;
    const int i = blockIdx.x * 4 + wid;       // query 0..4095
    float cr = 0.f;
#pragma unroll
    for (int ss = 0; ss < NKS; ++ss)
        cr += cross_part[(size_t)ss * CR_SLICE + (size_t)i * 128 + lane];
    const float neg = 2.0f * (cr + cvec[lane]) - p2[lane];   // -(dist) + const/row
    float m = neg;
    for (int off = 32; off > 0; off >>= 1) m = fmaxf(m, __shfl_xor(m, off, 64));
    float e = expf(neg - m);
    float ssum = e;
    for (int off = 32; off > 0; off >>= 1) ssum += __shfl_xor(ssum, off, 64);
    const float lse = m + logf(ssum);
    const int tcls = i >> 6;
    const float negt = __shfl(neg, tcls, 64);
    float v = -neg; int bi = lane;            // argmin dist == argmax neg, first on tie
    for (int off = 32; off > 0; off >>= 1) {
        const float ov = __shfl_xor(v, off, 64);
        const int   oi = __shfl_xor(bi, off, 64);
        if (ov < v || (ov == v && oi < bi)) { v = ov; bi = oi; }
    }
    if (lane == 0) { s_l[wid] = lse - negt; s_a[wid] = (bi == tcls) ? 1.0f : 0.0f; }
    __syncthreads();
    if (t == 0) {
        lpart[blockIdx.x]             = s_l[0] + s_l[1] + s_l[2] + s_l[3];
        lpart[LOSS_BLKS + blockIdx.x] = s_a[0] + s_a[1] + s_a[2] + s_a[3];
    }
}

__global__ __launch_bounds__(256) void writeout_kernel(const float* __restrict__ lpart,
                                                       float* __restrict__ out)
{
    __shared__ float s_red2[8];
    const int t = threadIdx.x;
    float l = 0.f, a = 0.f;
    for (int k = t; k < LOSS_BLKS; k += 256) {
        l += lpart[k];
        a += lpart[LOSS_BLKS + k];
    }
    l = waveReduceSum(l);
    a = waveReduceSum(a);
    const int lane = t & 63, wid = t >> 6;
    if (lane == 0) { s_red2[wid] = l; s_red2[4 + wid] = a; }
    __syncthreads();
    if (t == 0) {
        out[0] = (s_red2[0] + s_red2[1] + s_red2[2] + s_red2[3]) * (1.0f / NQ);
        out[1] = (s_red2[4] + s_red2[5] + s_red2[6] + s_red2[7]) * (1.0f / NQ);
    }
}

extern "C" void kernel_launch(void* const* d_in, const int* in_sizes, int n_in,
                              void* d_out, int out_size, void* d_ws, size_t ws_size,
                              hipStream_t stream)
{
    const float* xs      = (const float*)d_in[0];
    const float* xq      = (const float*)d_in[1];
    const float* W_share = (const float*)d_in[2];
    const float* b_share = (const float*)d_in[3];
    const float* W_att   = (const float*)d_in[4];
    const float* b_att   = (const float*)d_in[5];
    const float* W_fine  = (const float*)d_in[6];
    const float* b_fine  = (const float*)d_in[7];
    float* out = (float*)d_out;

    // workspace layout (bytes); arena holds zp_part -> gt_part -> cr_part
    // (sequentially dead, stream-ordered)
    char* ws = (char*)d_ws;
    __bf16* Xb      = (__bf16*)(ws);                   //   9,175,040
    __bf16* Wsb     = (__bf16*)(ws +   9175040);       //   6,553,600
    __bf16* Zsb     = (__bf16*)(ws +  15728640);       //  28,672,000
    __bf16* Wfb     = (__bf16*)(ws +  44400640);       //  20,480,000 natural [k][j]
    __bf16* WfTb    = (__bf16*)(ws +  64880640);       //  20,480,000 transposed [j][k]
    float*  arena   = (float*) (ws +  85360640);       //  20,971,520
    float*  zp_part = arena;                           //  10*204800*4 =  8,192,000
    float*  gt_part = arena;                           //  10*409600*4 = 16,384,000
    float*  cr_part = arena;                           //  10*524288*4 = 20,971,520
    __bf16* ub      = (__bf16*)(ws + 106332160);       //     819,200  [128][3200]
    __bf16* yb      = (__bf16*)(ws + 107151360);       //     819,200  [128][3200]
    __bf16* Gt      = (__bf16*)(ws + 107970560);       //     819,200  [128][3200]
    float*  pm      = (float*) (ws + 108789760);
    float*  wv      = (float*) (ws + 108790272);
    float*  p2v     = (float*) (ws + 108803072);
    float*  cvec    = (float*) (ws + 108803584);
    float*  lpart   = (float*) (ws + 108804096);       //       8,192

    conv_x_kernel<<<(M_PAD * D_IN / 4 + 255) / 256, 256, 0, stream>>>(xs, xq, Xb);
    {
        dim3 grid(D_FEAT / 32, D_IN / 32);
        convT_kernel<<<grid, 256, 0, stream>>>(W_share, Wsb, D_IN, D_FEAT);
    }
    // W_fine -> both layouts bf16
    {
        dim3 grid(D_FEAT / 32, D_FEAT / 32);
        convT2_kernel<<<grid, 256, 0, stream>>>(W_fine, Wfb, WfTb, D_FEAT, D_FEAT);
    }

    // z_share = relu(x @ W_share + b_share)  [4480][3200] bf16
    gemm_bf16<<<(D_FEAT / 128) * (M_PAD / 128), 256, 0, stream>>>(
        Xb, Wsb, b_share, Zsb, nullptr,
        D_FEAT, D_IN, D_IN / 32, M_PAD, 1, 0, D_FEAT / 128, M_PAD / 128);

    att1_kernel<<<C_CH, 256, 0, stream>>>(Zsb, pm);
    att2_kernel<<<1, C_CH, 0, stream>>>(pm, W_att, b_att, wv);

    // u = support means (bf16, padded to 128 rows)
    ut_kernel<<<128, 256, 0, stream>>>(Zsb, ub);

    // zp_part[ks][p][j] = partial u @ Wf   (A=u, Bt=WfTb)  M=64, N=3200, K=3200
    gemm_bf16<<<25 * NKS, 256, 0, stream>>>(
        ub, WfTb, nullptr, nullptr, zp_part,
        D_FEAT, D_FEAT, D_FEAT / 32 / NKS, N_CLASS, 0, ZP_SLICE, 25, 1);

    // y = w*(zp+b_fine), p2, c   (sums the 10 zp partials)
    y_kernel<<<128, 256, 0, stream>>>(zp_part, wv, b_fine, yb, p2v, cvec);

    // gt_part[ks][p][k] = partial y @ Wf^T  (A=yb, Bt=Wfb natural)  M=128, N=3200
    gemm_bf16<<<25 * NKS, 256, 0, stream>>>(
        yb, Wfb, nullptr, nullptr, gt_part,
        D_FEAT, D_FEAT, D_FEAT / 32 / NKS, 128, 0, GT_SLICE, 25, 1);

    // Gt bf16 = sum of slices
    gtsum_kernel<<<(GT_SLICE / 4 + 255) / 256, 256, 0, stream>>>(gt_part, Gt);

    // cr_part[ks][i][p] = partial zs_q @ Gt^T   [4096][128]
    gemm_bf16<<<32 * NKS, 256, 0, stream>>>(
        Zsb + (size_t)NS * D_FEAT, Gt, nullptr, nullptr, cr_part,
        128, D_FEAT, D_FEAT / 32 / NKS, NQ, 0, CR_SLICE, 1, 32);

    // per-query log-softmax + loss/acc -> block partials (no atomics)
    loss_kernel<<<LOSS_BLKS, 256, 0, stream>>>(cr_part, p2v, cvec, lpart);

    writeout_kernel<<<1, 256, 0, stream>>>(lpart, out);
}

// Round 7
// 277.785 us; speedup vs baseline: 2.1884x; 1.0998x over previous
//
#include <hip/hip_runtime.h>
#include <math.h>

// Problem constants
#define N_CLASS 64
#define N_SUPPORT 5
#define N_QUERY 64
#define D_IN 1024
#define C_CH 128
#define WIN 5
#define D_FEAT 3200            // C*WIN*WIN
#define NS 320                 // N_CLASS*N_SUPPORT
#define NQ 4096                // N_CLASS*N_QUERY
#define M_ROWS 4416            // NS+NQ
#define M_PAD 4480             // 35 * 128

#define ZP_SLICE  (N_CLASS * D_FEAT)          // 204800
#define GT_SLICE  (128 * D_FEAT)              // 409600
#define CR_SLICE  (NQ * 128)                  // 524288
#define NKS       10                          // split-K slices
#define LOSS_BLKS (NQ / 4)                    // 1024

// prep kernel block-range partition
#define PREP_X   4480                          // conv_x blocks
#define PREP_WS  3200                          // 100 x 32 (32x32 tiles)
#define PREP_WF  10000                         // 100 x 100

typedef __bf16 bf16x8 __attribute__((ext_vector_type(8)));
typedef __bf16 bf16x4 __attribute__((ext_vector_type(4)));
typedef float floatx4 __attribute__((ext_vector_type(4)));
typedef __attribute__((address_space(1))) const void* gptr_t;
typedef __attribute__((address_space(3))) void* lptr_t;

__device__ __forceinline__ float waveReduceSum(float v) {
    for (int off = 32; off > 0; off >>= 1) v += __shfl_xor(v, off, 64);
    return v;
}

// ------ fused prep: x->bf16 | W_share transpose->bf16 | W_fine dual-layout bf16 ------
__global__ __launch_bounds__(256) void prep_kernel(const float* __restrict__ xs,
                                                   const float* __restrict__ xq,
                                                   const float* __restrict__ W_share,
                                                   const float* __restrict__ W_fine,
                                                   __bf16* __restrict__ Xb,
                                                   __bf16* __restrict__ Wsb,
                                                   __bf16* __restrict__ Wfb,
                                                   __bf16* __restrict__ WfTb)
{
    __shared__ float tile[32][33];
    const int b = blockIdx.x;
    const int t = threadIdx.x;

    if (b < PREP_X) {
        // x (xs|xq|zero-pad) -> bf16 [M_PAD][1024], one float4 per thread
        const int e = (b * 256 + t) * 4;
        const int row = e >> 10;
        const int col = e & 1023;
        float4 v = make_float4(0.f, 0.f, 0.f, 0.f);
        if (row < NS)          v = *(const float4*)(xs + (size_t)row * D_IN + col);
        else if (row < M_ROWS) v = *(const float4*)(xq + (size_t)(row - NS) * D_IN + col);
        __bf16* o = Xb + (size_t)row * D_IN + col;
        o[0] = (__bf16)v.x; o[1] = (__bf16)v.y; o[2] = (__bf16)v.z; o[3] = (__bf16)v.w;
        return;
    }
    const int tx = t & 31;
    const int ty = t >> 5;
    if (b < PREP_X + PREP_WS) {
        // W_share [1024][3200] -> Wsb [3200][1024] bf16
        const int tb = b - PREP_X;
        const int n0 = (tb % 100) * 32;
        const int k0 = (tb / 100) * 32;
#pragma unroll
        for (int i = ty; i < 32; i += 8)
            tile[i][tx] = W_share[(size_t)(k0 + i) * D_FEAT + n0 + tx];
        __syncthreads();
#pragma unroll
        for (int i = ty; i < 32; i += 8)
            Wsb[(size_t)(n0 + i) * D_IN + k0 + tx] = (__bf16)tile[tx][i];
        return;
    }
    // W_fine [3200][3200] -> Wfb natural + WfTb transposed, bf16
    {
        const int tb = b - PREP_X - PREP_WS;
        const int n0 = (tb % 100) * 32;
        const int k0 = (tb / 100) * 32;
#pragma unroll
        for (int i = ty; i < 32; i += 8) {
            const float v = W_fine[(size_t)(k0 + i) * D_FEAT + n0 + tx];
            Wfb[(size_t)(k0 + i) * D_FEAT + n0 + tx] = (__bf16)v;
            tile[i][tx] = v;
        }
        __syncthreads();
#pragma unroll
        for (int i = ty; i < 32; i += 8)
            WfTb[(size_t)(n0 + i) * D_FEAT + k0 + tx] = (__bf16)tile[tx][i];
    }
}

// ---------------- MFMA GEMM: out = act(A @ Bt^T + bias) or split-K partials --------
// A [..][strideK] bf16, Bt [N][strideK] bf16. 128x128 tile, BK=64 (2 x BK32 subtiles
// per barrier pair -> half the barrier events of the BK32 version; LDS 32 KB).
// grid = nbx*nby*nks (1D). XOR-swizzled LDS per subtile (conflict-free),
// global_load_lds width-16 staging.
// sliceStride>0: plain-store fp32 partial at out_f32 + ks*sliceStride (no bias/relu).
__global__ __launch_bounds__(256) void gemm_bf16(const __bf16* __restrict__ A,
                                                 const __bf16* __restrict__ Bt,
                                                 const float* __restrict__ bias,
                                                 __bf16* __restrict__ out_bf,
                                                 float* __restrict__ out_f32,
                                                 int N, int strideK, int kIters,
                                                 int Mout, int relu, int sliceStride,
                                                 int nbx, int nby)
{
    __shared__ __align__(16) char smem[32768];   // sA: sub0@0 sub1@8192 | sB: @16384,@24576

    // ---- block remap: ksplit + XCD-grouped columns ----
    int bx, by, ks;
    {
        const int nbxy = nbx * nby;
        ks = blockIdx.x / nbxy;
        const int b = blockIdx.x - ks * nbxy;
        const int fg = nbx >> 3;
        const int full = fg * 8 * nby;
        if (b < full) {
            const int g = b / (8 * nby);
            const int r = b - g * 8 * nby;
            bx = g * 8 + (r & 7);
            by = r >> 3;
        } else {
            const int rem = nbx - fg * 8;
            const int r = b - full;
            bx = fg * 8 + r % rem;
            by = r / rem;
        }
    }

    const int t    = threadIdx.x;
    const int lane = t & 63;
    const int w    = t >> 6;
    const int wm   = w >> 1;
    const int wn   = w & 1;
    const int bm   = by * 128;
    const int bn   = bx * 128;

    const int q    = lane >> 4;
    const int r16  = lane & 15;
    const int sw   = (r16 >> 1) & 3;
    const int cA   = (q ^ sw) * 8;

    const int srow   = w * 16 + (lane >> 2);
    const int sglob8 = (((lane & 3) ^ ((lane >> 3) & 3))) * 8;

    const int kBase = ks * kIters * 64;
    floatx4 acc[4][4] = {};

    for (int ki = 0; ki < kIters; ++ki) {
        const int k0 = kBase + ki * 64;
        __syncthreads();
#pragma unroll
        for (int s = 0; s < 2; ++s) {
#pragma unroll
            for (int j = 0; j < 2; ++j) {
                const __bf16* ga = A  + (size_t)(bm + j * 64 + srow) * strideK
                                      + k0 + s * 32 + sglob8;
                const __bf16* gb = Bt + (size_t)(bn + j * 64 + srow) * strideK
                                      + k0 + s * 32 + sglob8;
                char* la = smem +         s * 8192 + (j * 256 + w * 64) * 16;
                char* lb = smem + 16384 + s * 8192 + (j * 256 + w * 64) * 16;
                __builtin_amdgcn_global_load_lds((gptr_t)ga, (lptr_t)la, 16, 0, 0);
                __builtin_amdgcn_global_load_lds((gptr_t)gb, (lptr_t)lb, 16, 0, 0);
            }
        }
        __syncthreads();

#pragma unroll
        for (int s = 0; s < 2; ++s) {
            const __bf16* sAe = (const __bf16*)(smem +         s * 8192);
            const __bf16* sBe = (const __bf16*)(smem + 16384 + s * 8192);
            bf16x8 av[4], bv[4];
#pragma unroll
            for (int mi = 0; mi < 4; ++mi)
                av[mi] = *(const bf16x8*)(sAe + ((wm * 64 + mi * 16 + r16) * 32 + cA));
#pragma unroll
            for (int ni = 0; ni < 4; ++ni)
                bv[ni] = *(const bf16x8*)(sBe + ((wn * 64 + ni * 16 + r16) * 32 + cA));
#pragma unroll
            for (int mi = 0; mi < 4; ++mi)
#pragma unroll
                for (int ni = 0; ni < 4; ++ni)
                    acc[mi][ni] = __builtin_amdgcn_mfma_f32_16x16x32_bf16(
                        av[mi], bv[ni], acc[mi][ni], 0, 0, 0);
        }
    }

    // epilogue: C/D layout col=lane&15, row=(lane>>4)*4+reg
#pragma unroll
    for (int ni = 0; ni < 4; ++ni) {
        const int col = bn + wn * 64 + ni * 16 + r16;
        const float bcol = sliceStride ? 0.f : bias[col];
#pragma unroll
        for (int mi = 0; mi < 4; ++mi) {
#pragma unroll
            for (int reg = 0; reg < 4; ++reg) {
                const int row = bm + wm * 64 + mi * 16 + q * 4 + reg;
                if (row < Mout) {
                    if (sliceStride) {
                        out_f32[(size_t)ks * sliceStride + (size_t)row * N + col] =
                            acc[mi][ni][reg];
                    } else {
                        float v = acc[mi][ni][reg] + bcol;
                        if (relu) v = fmaxf(v, 0.f);
                        if (out_f32) out_f32[(size_t)row * N + col] = v;
                        else         out_bf [(size_t)row * N + col] = (__bf16)v;
                    }
                }
            }
        }
    }
}

// ------- u[p][k] = support mean (bf16, pad rows 0) + per-class channel pools --------
__global__ __launch_bounds__(256) void ut_kernel(const __bf16* __restrict__ z_share,
                                                 __bf16* __restrict__ u,
                                                 float* __restrict__ upool)
{
    __shared__ float srow_[D_FEAT];
    const int p = blockIdx.x;        // 0..127
    const int t = threadIdx.x;
    if (p >= N_CLASS) {
        for (int k = t; k < D_FEAT; k += 256) u[(size_t)p * D_FEAT + k] = (__bf16)0.f;
        return;
    }
    const __bf16* base = z_share + (size_t)(p * N_SUPPORT) * D_FEAT;
    for (int k = t; k < D_FEAT; k += 256) {
        float s = 0.f;
#pragma unroll
        for (int ss = 0; ss < N_SUPPORT; ++ss) s += (float)base[(size_t)ss * D_FEAT + k];
        s *= (1.0f / N_SUPPORT);
        u[(size_t)p * D_FEAT + k] = (__bf16)s;
        srow_[k] = s;
    }
    __syncthreads();
    if (t < C_CH) {
        float pool = 0.f;
#pragma unroll
        for (int win = 0; win < 25; ++win) pool += srow_[t * 25 + win];
        upool[(size_t)p * C_CH + t] = pool;
    }
}

// ------------- att: pooled mean (from upool) -> matvec -> softmax -> w[3200] --------
__global__ __launch_bounds__(128) void att2_kernel(const float* __restrict__ upool,
                                                   const float* __restrict__ W_att,
                                                   const float* __restrict__ b_att,
                                                   float* __restrict__ wvec)
{
    __shared__ float s_pm[C_CH];
    __shared__ float s_att[C_CH];
    __shared__ float s_diag[C_CH];
    const int c = threadIdx.x;
    float a = 0.f;
    for (int p = 0; p < N_CLASS; ++p) a += upool[(size_t)p * C_CH + c];
    s_pm[c] = a * (1.0f / (N_CLASS * 25));
    __syncthreads();
    float acc = b_att[c];
    for (int k = 0; k < C_CH; ++k) acc += s_pm[k] * W_att[k * C_CH + c];
    s_att[c] = acc;
    __syncthreads();
    float m = -INFINITY;
    for (int k = 0; k < C_CH; ++k) m = fmaxf(m, s_att[k]);
    float s = 0.f;
    for (int k = 0; k < C_CH; ++k) s += expf(s_att[k] - m);
    s_diag[c] = expf(acc - m) / s * (float)C_CH;
    __syncthreads();
    for (int j = c; j < D_FEAT; j += C_CH) wvec[j] = s_diag[j / 25];
}

// ---------------- y = w*(sum zp_part + bf) bf16 [128 pad][3200]; p2; c --------------
__global__ __launch_bounds__(256) void y_kernel(const float* __restrict__ zp_part,
                                                const float* __restrict__ wv,
                                                const float* __restrict__ bf,
                                                __bf16* __restrict__ y,
                                                float* __restrict__ p2,
                                                float* __restrict__ cvec)
{
    __shared__ float s_red2[8];
    const int p = blockIdx.x;        // 0..127
    const int t = threadIdx.x;
    if (p >= N_CLASS) {
        for (int j = t; j < D_FEAT; j += 256) y[(size_t)p * D_FEAT + j] = (__bf16)0.f;
        return;
    }
    float s2 = 0.f, sc = 0.f;
    for (int j = t; j < D_FEAT; j += 256) {
        float zpf = bf[j];
#pragma unroll
        for (int ss = 0; ss < NKS; ++ss)
            zpf += zp_part[(size_t)ss * ZP_SLICE + (size_t)p * D_FEAT + j];
        const float wj = wv[j];
        y[(size_t)p * D_FEAT + j] = (__bf16)(wj * zpf);
        s2 += wj * zpf * zpf;
        sc += bf[j] * wj * zpf;
    }
    s2 = waveReduceSum(s2);
    sc = waveReduceSum(sc);
    const int lane = t & 63, wid = t >> 6;
    if (lane == 0) { s_red2[wid] = s2; s_red2[4 + wid] = sc; }
    __syncthreads();
    if (t == 0) {
        p2[p]   = s_red2[0] + s_red2[1] + s_red2[2] + s_red2[3];
        cvec[p] = s_red2[4] + s_red2[5] + s_red2[6] + s_red2[7];
    }
}

// ---------------- Gt[p][k] bf16 = sum of 10 fp32 slices [128][3200] ----------------
__global__ __launch_bounds__(256) void gtsum_kernel(const float* __restrict__ gp,
                                                    __bf16* __restrict__ Gt)
{
    const int i4 = blockIdx.x * 256 + threadIdx.x;     // over 409600/4
    if (i4 >= GT_SLICE / 4) return;
    float4 s = make_float4(0.f, 0.f, 0.f, 0.f);
#pragma unroll
    for (int ss = 0; ss < NKS; ++ss) {
        const float4 v = *(const float4*)(gp + (size_t)ss * GT_SLICE + i4 * 4);
        s.x += v.x; s.y += v.y; s.z += v.z; s.w += v.w;
    }
    bf16x4 o = { (__bf16)s.x, (__bf16)s.y, (__bf16)s.z, (__bf16)s.w };
    *(bf16x4*)(Gt + (size_t)i4 * 4) = o;
}

// ---------------- softmax/loss: one wave per query, block partials (no atomics) -----
__global__ __launch_bounds__(256) void loss_kernel(const float* __restrict__ cross_part,
                                                   const float* __restrict__ p2,
                                                   const float* __restrict__ cvec,
                                                   float* __restrict__ lpart)
{
    __shared__ float s_l[4], s_a[4];
    const int t = threadIdx.x;
    const int lane = t & 63, wid = t >> 6;
    const int i = blockIdx.x * 4 + wid;       // query 0..4095
    float cr = 0.f;
#pragma unroll
    for (int ss = 0; ss < NKS; ++ss)
        cr += cross_part[(size_t)ss * CR_SLICE + (size_t)i * 128 + lane];
    const float neg = 2.0f * (cr + cvec[lane]) - p2[lane];   // -(dist) + const/row
    float m = neg;
    for (int off = 32; off > 0; off >>= 1) m = fmaxf(m, __shfl_xor(m, off, 64));
    float e = expf(neg - m);
    float ssum = e;
    for (int off = 32; off > 0; off >>= 1) ssum += __shfl_xor(ssum, off, 64);
    const float lse = m + logf(ssum);
    const int tcls = i >> 6;
    const float negt = __shfl(neg, tcls, 64);
    float v = -neg; int bi = lane;            // argmin dist == argmax neg, first on tie
    for (int off = 32; off > 0; off >>= 1) {
        const float ov = __shfl_xor(v, off, 64);
        const int   oi = __shfl_xor(bi, off, 64);
        if (ov < v || (ov == v && oi < bi)) { v = ov; bi = oi; }
    }
    if (lane == 0) { s_l[wid] = lse - negt; s_a[wid] = (bi == tcls) ? 1.0f : 0.0f; }
    __syncthreads();
    if (t == 0) {
        lpart[blockIdx.x]             = s_l[0] + s_l[1] + s_l[2] + s_l[3];
        lpart[LOSS_BLKS + blockIdx.x] = s_a[0] + s_a[1] + s_a[2] + s_a[3];
    }
}

__global__ __launch_bounds__(256) void writeout_kernel(const float* __restrict__ lpart,
                                                       float* __restrict__ out)
{
    __shared__ float s_red2[8];
    const int t = threadIdx.x;
    float l = 0.f, a = 0.f;
    for (int k = t; k < LOSS_BLKS; k += 256) {
        l += lpart[k];
        a += lpart[LOSS_BLKS + k];
    }
    l = waveReduceSum(l);
    a = waveReduceSum(a);
    const int lane = t & 63, wid = t >> 6;
    if (lane == 0) { s_red2[wid] = l; s_red2[4 + wid] = a; }
    __syncthreads();
    if (t == 0) {
        out[0] = (s_red2[0] + s_red2[1] + s_red2[2] + s_red2[3]) * (1.0f / NQ);
        out[1] = (s_red2[4] + s_red2[5] + s_red2[6] + s_red2[7]) * (1.0f / NQ);
    }
}

extern "C" void kernel_launch(void* const* d_in, const int* in_sizes, int n_in,
                              void* d_out, int out_size, void* d_ws, size_t ws_size,
                              hipStream_t stream)
{
    const float* xs      = (const float*)d_in[0];
    const float* xq      = (const float*)d_in[1];
    const float* W_share = (const float*)d_in[2];
    const float* b_share = (const float*)d_in[3];
    const float* W_att   = (const float*)d_in[4];
    const float* b_att   = (const float*)d_in[5];
    const float* W_fine  = (const float*)d_in[6];
    const float* b_fine  = (const float*)d_in[7];
    float* out = (float*)d_out;

    // workspace layout (bytes); arena holds upool -> zp_part -> gt_part -> cr_part
    // (sequentially dead, stream-ordered)
    char* ws = (char*)d_ws;
    __bf16* Xb      = (__bf16*)(ws);                   //   9,175,040
    __bf16* Wsb     = (__bf16*)(ws +   9175040);       //   6,553,600
    __bf16* Zsb     = (__bf16*)(ws +  15728640);       //  28,672,000
    __bf16* Wfb     = (__bf16*)(ws +  44400640);       //  20,480,000 natural [k][j]
    __bf16* WfTb    = (__bf16*)(ws +  64880640);       //  20,480,000 transposed [j][k]
    float*  arena   = (float*) (ws +  85360640);       //  20,971,520
    float*  upool   = arena;                           //  64*128*4 (dead before zp)
    float*  zp_part = arena;                           //  10*204800*4 =  8,192,000
    float*  gt_part = arena;                           //  10*409600*4 = 16,384,000
    float*  cr_part = arena;                           //  10*524288*4 = 20,971,520
    __bf16* ub      = (__bf16*)(ws + 106332160);       //     819,200  [128][3200]
    __bf16* yb      = (__bf16*)(ws + 107151360);       //     819,200  [128][3200]
    __bf16* Gt      = (__bf16*)(ws + 107970560);       //     819,200  [128][3200]
    float*  wv      = (float*) (ws + 108789760);       //      12,800
    float*  p2v     = (float*) (ws + 108802560);
    float*  cvec    = (float*) (ws + 108803072);
    float*  lpart   = (float*) (ws + 108803584);       //       8,192

    // fused conversions (x | W_share^T | W_fine dual)
    prep_kernel<<<PREP_X + PREP_WS + PREP_WF, 256, 0, stream>>>(
        xs, xq, W_share, W_fine, Xb, Wsb, Wfb, WfTb);

    // z_share = relu(x @ W_share + b_share)  [4480][3200] bf16
    gemm_bf16<<<(D_FEAT / 128) * (M_PAD / 128), 256, 0, stream>>>(
        Xb, Wsb, b_share, Zsb, nullptr,
        D_FEAT, D_IN, D_IN / 64, M_ROWS, 1, 0, D_FEAT / 128, M_PAD / 128);

    // u = support means (bf16, padded to 128 rows) + channel pools
    ut_kernel<<<128, 256, 0, stream>>>(Zsb, ub, upool);
    att2_kernel<<<1, C_CH, 0, stream>>>(upool, W_att, b_att, wv);

    // zp_part[ks][p][j] = partial u @ Wf   (A=u, Bt=WfTb)  M=64, N=3200, K=3200
    gemm_bf16<<<25 * NKS, 256, 0, stream>>>(
        ub, WfTb, nullptr, nullptr, zp_part,
        D_FEAT, D_FEAT, 5, N_CLASS, 0, ZP_SLICE, 25, 1);

    // y = w*(zp+b_fine), p2, c   (sums the 10 zp partials)
    y_kernel<<<128, 256, 0, stream>>>(zp_part, wv, b_fine, yb, p2v, cvec);

    // gt_part[ks][p][k] = partial y @ Wf^T  (A=yb, Bt=Wfb natural)  M=128, N=3200
    gemm_bf16<<<25 * NKS, 256, 0, stream>>>(
        yb, Wfb, nullptr, nullptr, gt_part,
        D_FEAT, D_FEAT, 5, 128, 0, GT_SLICE, 25, 1);

    // Gt bf16 = sum of slices
    gtsum_kernel<<<(GT_SLICE / 4 + 255) / 256, 256, 0, stream>>>(gt_part, Gt);

    // cr_part[ks][i][p] = partial zs_q @ Gt^T   [4096][128]
    gemm_bf16<<<32 * NKS, 256, 0, stream>>>(
        Zsb + (size_t)NS * D_FEAT, Gt, nullptr, nullptr, cr_part,
        128, D_FEAT, 5, NQ, 0, CR_SLICE, 1, 32);

    // per-query log-softmax + loss/acc -> block partials (no atomics)
    loss_kernel<<<LOSS_BLKS, 256, 0, stream>>>(cr_part, p2v, cvec, lpart);

    writeout_kernel<<<1, 256, 0, stream>>>(lpart, out);
}